// Round 5
// baseline (483.093 us; speedup 1.0000x reference)
//
#include <hip/hip_runtime.h>
#include <math.h>

#define N_NODES 20000
#define E_EDGES 320000
#define IN_CH   300
#define HID     100
#define R_REL   50
#define NB      8
#define CLS     3
#define NQ      64
#define OUTW    800   // NB * HID
#define ZW      104   // Z row stride (ushorts): 208-B rows (16B-aligned), exact fit
#define KP1     320
#define KP2     128
#define MPAD    20224 // 79 * 256 (row-chunk padded M for A bf16 buffers)
#define NPAIR   79    // MPAD / 256
#define GEMM_RG 48    // row-groups; grid = 10 col-blocks * 48 = 480 blocks
#define SCAN_BLKS ((N_NODES + 255) / 256)   // 79

typedef unsigned short ushort_t;
typedef __attribute__((ext_vector_type(8))) short     short8;
typedef __attribute__((ext_vector_type(8))) unsigned short ushort8;
typedef __attribute__((ext_vector_type(4))) float     f32x4;
typedef __attribute__((ext_vector_type(2))) float     f32x2;

__device__ __forceinline__ ushort_t f2bf_rne(float f) {   // round-nearest-even
    unsigned u = __float_as_uint(f);
    unsigned r = (u + 0x7fffu + ((u >> 16) & 1u)) >> 16;
    return (ushort_t)r;
}
__device__ __forceinline__ float bf2f(ushort_t u) {
    return __uint_as_float((unsigned)u << 16);
}

// ============================ CSR build =================================
__global__ __launch_bounds__(256) void hist2_kernel(
        const int* __restrict__ ei, int* __restrict__ dd,
        int* __restrict__ ds) {
    int e = blockIdx.x * 256 + threadIdx.x;
    if (e < E_EDGES) {
        atomicAdd(&dd[ei[E_EDGES + e]], 1);
        atomicAdd(&ds[ei[e]], 1);
    }
}

// dual-set scans: blockIdx selects (deg_d...) or (deg_s...) set
__global__ __launch_bounds__(256) void scan1_both(
        const int* __restrict__ deg_d, int* __restrict__ rp_d, int* __restrict__ bsum_d,
        const int* __restrict__ deg_s, int* __restrict__ rp_s, int* __restrict__ bsum_s) {
    int set = blockIdx.x / SCAN_BLKS, blk = blockIdx.x % SCAN_BLKS;
    const int* deg = set ? deg_s : deg_d;
    int* rowptr    = set ? rp_s  : rp_d;
    int* bsum      = set ? bsum_s : bsum_d;
    __shared__ int s[256];
    int tid = threadIdx.x;
    int idx = blk * 256 + tid;
    int v = (idx < N_NODES) ? deg[idx] : 0;
    s[tid] = v; __syncthreads();
    #pragma unroll
    for (int off = 1; off < 256; off <<= 1) {
        int t = (tid >= off) ? s[tid - off] : 0;
        __syncthreads();
        s[tid] += t;
        __syncthreads();
    }
    if (idx < N_NODES) rowptr[idx] = s[tid] - v;   // exclusive
    if (tid == 255) bsum[blk] = s[255];
}

__global__ __launch_bounds__(128) void scan2_both(
        int* __restrict__ bsum_d, int* __restrict__ rp_d,
        int* __restrict__ bsum_s, int* __restrict__ rp_s) {
    int* bsum   = blockIdx.x ? bsum_s : bsum_d;
    int* rowptr = blockIdx.x ? rp_s   : rp_d;
    __shared__ int s[128];
    int tid = threadIdx.x;
    int v = (tid < SCAN_BLKS) ? bsum[tid] : 0;
    s[tid] = v; __syncthreads();
    #pragma unroll
    for (int off = 1; off < 128; off <<= 1) {
        int t = (tid >= off) ? s[tid - off] : 0;
        __syncthreads();
        s[tid] += t;
        __syncthreads();
    }
    if (tid < SCAN_BLKS) bsum[tid] = s[tid] - v;   // exclusive
    if (tid == 0) rowptr[N_NODES] = E_EDGES;
}

__global__ __launch_bounds__(256) void scan3_both(
        int* __restrict__ rp_d, const int* __restrict__ bsum_d, int* __restrict__ cur_d,
        int* __restrict__ rp_s, const int* __restrict__ bsum_s, int* __restrict__ cur_s) {
    int set = blockIdx.x / SCAN_BLKS, blk = blockIdx.x % SCAN_BLKS;
    int* rowptr      = set ? rp_s   : rp_d;
    const int* bsum  = set ? bsum_s : bsum_d;
    int* cursor      = set ? cur_s  : cur_d;
    int idx = blk * 256 + threadIdx.x;
    if (idx < N_NODES) {
        int v = rowptr[idx] + bsum[blk];
        rowptr[idx] = v;
        cursor[idx] = v;
    }
}

// fused scatter: dst-CSR key (src,rel), src-CSR key (rel), and zidx map
__global__ __launch_bounds__(256) void scatter_both(
        const int* __restrict__ ei, const int* __restrict__ et,
        int* __restrict__ cur_d, int* __restrict__ cur_s,
        int* __restrict__ skey, int* __restrict__ skey_s,
        int* __restrict__ zidx) {
    int e = blockIdx.x * 256 + threadIdx.x;
    if (e >= E_EDGES) return;
    int s = ei[e], d = ei[E_EDGES + e], rt = et[e];
    int p = atomicAdd(&cur_d[d], 1);
    skey[p] = (s << 6) | rt;                 // dst-order: (src, rel)
    int qp = atomicAdd(&cur_s[s], 1);
    skey_s[qp] = rt;                         // src-order: rel only
    zidx[p] = qp;                            // dst-slot -> Z row (src-slot)
}

// ==== fused preprocessing: Bt1, Bt2, cvt_pad(x), hbA-zero, deg-zero ====
// One dispatch replaces 4: fewer launch gaps, all regions independent.
#define PREP_N1 (OUTW * KP1)                 // Bt1
#define PREP_N2 (OUTW * KP2)                 // Bt2
#define PREP_NC (MPAD * (KP1 / 8))           // cvt_pad x (ushort8 chunks)
#define PREP_NZ (MPAD * (KP2 / 8))           // hbA zero (ushort8 chunks)
#define PREP_TOT (PREP_N1 + PREP_N2 + PREP_NC + PREP_NZ + N_NODES)
__global__ __launch_bounds__(256) void prep_kernel(
        const float* __restrict__ basis1, ushort_t* __restrict__ Bt1,
        const float* __restrict__ basis2, ushort_t* __restrict__ Bt2,
        const float* __restrict__ x, ushort_t* __restrict__ xbA,
        ushort_t* __restrict__ hbA,
        int* __restrict__ dd, int* __restrict__ ds) {
    int idx = blockIdx.x * 256 + threadIdx.x;
    if (idx < PREP_N1) {
        int n = idx / KP1, k = idx - n * KP1;
        int b = n / HID, o = n - b * HID;
        float v = (k < IN_CH) ? basis1[((size_t)b * IN_CH + k) * HID + o] : 0.f;
        Bt1[idx] = f2bf_rne(v);
        return;
    }
    idx -= PREP_N1;
    if (idx < PREP_N2) {
        int n = idx / KP2, k = idx - n * KP2;
        int b = n / HID, o = n - b * HID;
        float v = (k < HID) ? basis2[((size_t)b * HID + k) * HID + o] : 0.f;
        Bt2[idx] = f2bf_rne(v);
        return;
    }
    idx -= PREP_N2;
    if (idx < PREP_NC) {                       // x -> bf16 padded
        constexpr int CH = KP1 / 8;
        int n = idx / CH, c = idx - n * CH;
        int k = c * 8;
        float v[8];
        if (n < N_NODES && k + 8 <= IN_CH) {
            float4 f0 = *(const float4*)&x[(size_t)n * IN_CH + k];
            float4 f1 = *(const float4*)&x[(size_t)n * IN_CH + k + 4];
            v[0]=f0.x; v[1]=f0.y; v[2]=f0.z; v[3]=f0.w;
            v[4]=f1.x; v[5]=f1.y; v[6]=f1.z; v[7]=f1.w;
        } else {
            #pragma unroll
            for (int i = 0; i < 8; i++)
                v[i] = (n < N_NODES && k + i < IN_CH) ? x[(size_t)n * IN_CH + k + i] : 0.f;
        }
        ushort8 hv;
        #pragma unroll
        for (int i = 0; i < 8; i++) hv[i] = f2bf_rne(v[i]);
        *(ushort8*)&xbA[(size_t)n * KP1 + k] = hv;
        return;
    }
    idx -= PREP_NC;
    if (idx < PREP_NZ) {                       // hbA zero (pads must be 0)
        ushort8 z = {};
        *(ushort8*)&hbA[(size_t)idx * 8] = z;
        return;
    }
    idx -= PREP_NZ;
    if (idx < N_NODES) { dd[idx] = 0; ds[idx] = 0; }
}

// ---- MFMA GEMM + fused q/k partial dots ----
// xbh[M,800](bf16) = Ab[M,KP](bf16) * B[KP,800]
// 480 blocks = 10 col-blocks (80 cols) x 48 row-groups, 512 threads.
// XCD-affine mapping (FETCH ~= A read once, verified r3).
// qk fusion: xbq[n,b] = sum_c xbh[n,b*100+c] q[c]. Each cb's 80-col window
// intersects 1 or 2 basis slices; (b, part) -> (cb, slot) is bijective
// (verified by enumerating all 16 pairs), so partial dots are written
// WITHOUT atomics to xq/xk[n][b][2]; msg_soft sums the pair.
// BUGFIX r4->r5: single-slice blocks (bHi==bLo: cb 0,4,5,9) must route ALL
// columns to the Lo accumulator (split pushed past the window); previously
// split=bHi*100 <= col0 sent everything to the discarded Hi registers.
template<int KP>
__global__ __launch_bounds__(512, 4) void gemm_mfma(
        const ushort_t* __restrict__ Ab, const ushort_t* __restrict__ Bt,
        ushort_t* __restrict__ xbh, int M,
        const float* __restrict__ qw, const float* __restrict__ kw,
        float* __restrict__ xq, float* __restrict__ xk) {
    constexpr int KSTEPS = KP / 32;           // 10 (layer1) / 4 (layer2)
    constexpr int SW = KP + 8;                // LDS col stride (ushorts)
    constexpr int CH = KP / 8;
    __shared__ ushort_t Bs[80 * SW];          // 52.5 KB (L1) / 21.3 KB (L2)
    __shared__ float sqk[2 * HID];            // q then k (800 B)
    int tid = threadIdx.x, lane = tid & 63, wave = tid >> 6;
    int ml = lane & 15, quad = lane >> 4;
    // XCD-affine de-swizzle: b = (rg&7) + 8*cb + 80*(rg>>3)
    int b = blockIdx.x;
    int xcd = b & 7, qq = b >> 3;
    int cb = qq % 10;                         // 10 col blocks of 80
    int rg = xcd + 8 * (qq / 10);             // 0..47
    int col0 = cb * 80;

    // ---- stage B tile once (coalesced 16B chunks) + q/k vectors ----
    if (tid < 2 * HID) sqk[tid] = (tid < HID) ? qw[tid] : kw[tid - HID];
    for (int t = tid; t < 80 * CH; t += 512) {
        int c = t / CH, ch = t - c * CH;
        *(ushort8*)&Bs[c * SW + ch * 8] =
            *(const ushort8*)&Bt[(size_t)(col0 + c) * KP + ch * 8];
    }
    __syncthreads();                          // the ONLY barrier

    const ushort_t* bb = &Bs[(size_t)ml * SW + quad * 8];

    // per-lane qk-partial constants for this col-block
    int bLo = col0 / 100, bHi = (col0 + 79) / 100;
    int split = (bHi != bLo) ? bHi * 100 : (col0 + 160);   // unreachable if 1 slice
    int slotLo = ((bLo * 100) / 80 == cb) ? 0 : 1;
    int slotHi = ((bHi * 100) / 80 == cb) ? 0 : 1;
    float qv[5], kv[5];
    int himask = 0;
    #pragma unroll
    for (int nt = 0; nt < 5; nt++) {
        int c = col0 + nt * 16 + ml;
        int cm = c % 100;
        qv[nt] = sqk[cm]; kv[nt] = sqk[100 + cm];
        if (c >= split) himask |= 1 << nt;
    }

    for (int g = rg; g < NPAIR; g += GEMM_RG) {
        int rbase = g * 256 + wave * 32;      // this wave's 32 rows
        const ushort_t* ar0 = Ab + (size_t)(rbase + ml) * KP + quad * 8;
        const ushort_t* ar1 = ar0 + (size_t)16 * KP;
        short8 a0[KSTEPS], a1[KSTEPS];
        #pragma unroll
        for (int ks = 0; ks < KSTEPS; ks++) {
            a0[ks] = *(const short8*)(ar0 + ks * 32);
            a1[ks] = *(const short8*)(ar1 + ks * 32);
        }
        f32x4 acc0[5] = {}, acc1[5] = {};
        #pragma unroll
        for (int ks = 0; ks < KSTEPS; ks++) {
            short8 bf[5];
            #pragma unroll
            for (int nt = 0; nt < 5; nt++)
                bf[nt] = *(const short8*)(bb + nt * 16 * SW + ks * 32);
            #pragma unroll
            for (int nt = 0; nt < 5; nt++) {
                acc0[nt] = __builtin_amdgcn_mfma_f32_16x16x32_bf16(
                               a0[ks], bf[nt], acc0[nt], 0, 0, 0);
                acc1[nt] = __builtin_amdgcn_mfma_f32_16x16x32_bf16(
                               a1[ks], bf[nt], acc1[nt], 0, 0, 0);
            }
        }
        // epilogue (C layout: row = quad*4 + r, col = nt*16 + ml)
        #pragma unroll
        for (int nt = 0; nt < 5; nt++) {
            #pragma unroll
            for (int r = 0; r < 4; r++) {
                int g0 = rbase + quad * 4 + r;
                if (g0 < M)
                    xbh[(size_t)g0 * OUTW + col0 + nt * 16 + ml] =
                        f2bf_rne(acc0[nt][r]);
                int g1 = g0 + 16;
                if (g1 < M)
                    xbh[(size_t)g1 * OUTW + col0 + nt * 16 + ml] =
                        f2bf_rne(acc1[nt][r]);
            }
        }
        // fused q/k partial dots: reduce over ml lanes, write per (row,b,slot)
        #pragma unroll
        for (int r = 0; r < 4; r++) {
            float pqL = 0, pqH = 0, pkL = 0, pkH = 0;   // acc0 rows
            float sqL = 0, sqH = 0, skL = 0, skH = 0;   // acc1 rows
            #pragma unroll
            for (int nt = 0; nt < 5; nt++) {
                float v0 = acc0[nt][r], v1 = acc1[nt][r];
                if (himask & (1 << nt)) {
                    pqH = fmaf(v0, qv[nt], pqH); pkH = fmaf(v0, kv[nt], pkH);
                    sqH = fmaf(v1, qv[nt], sqH); skH = fmaf(v1, kv[nt], skH);
                } else {
                    pqL = fmaf(v0, qv[nt], pqL); pkL = fmaf(v0, kv[nt], pkL);
                    sqL = fmaf(v1, qv[nt], sqL); skL = fmaf(v1, kv[nt], skL);
                }
            }
            #pragma unroll
            for (int off = 1; off < 16; off <<= 1) {
                pqL += __shfl_xor(pqL, off); pqH += __shfl_xor(pqH, off);
                pkL += __shfl_xor(pkL, off); pkH += __shfl_xor(pkH, off);
                sqL += __shfl_xor(sqL, off); sqH += __shfl_xor(sqH, off);
                skL += __shfl_xor(skL, off); skH += __shfl_xor(skH, off);
            }
            if (ml == 0) {
                int r0 = rbase + quad * 4 + r, r1 = r0 + 16;
                int iLo0 = r0 * 16 + bLo * 2 + slotLo;
                int iLo1 = r1 * 16 + bLo * 2 + slotLo;
                xq[iLo0] = pqL; xk[iLo0] = pkL;
                xq[iLo1] = sqL; xk[iLo1] = skL;
                if (bHi != bLo) {
                    int iHi0 = r0 * 16 + bHi * 2 + slotHi;
                    int iHi1 = r1 * 16 + bHi * 2 + slotHi;
                    xq[iHi0] = pqH; xk[iHi0] = pkH;
                    xq[iHi1] = sqH; xk[iHi1] = skH;
                }
            }
        }
    }
}

// ==== src-major, batched-4 Z rows; comp in LDS; keys via register window ====
// lane = eg*16 + c16; covers channels [8*c16, 8*c16+8) of edge p0+eg.
__global__ __launch_bounds__(256) void compute_z(
        const int* __restrict__ rowptr_s, const int* __restrict__ skey_s,
        const float* __restrict__ comp, const ushort_t* __restrict__ xbh,
        ushort_t* __restrict__ Z) {
    __shared__ float scomp[R_REL * NB];   // 1.6 KB
    int tid = threadIdx.x;
    for (int i = tid; i < R_REL * NB; i += 256) scomp[i] = comp[i];
    __syncthreads();
    int wave = tid >> 6, lane = tid & 63;
    int s = blockIdx.x * 4 + wave;
    if (s >= N_NODES) return;
    int beg = rowptr_s[s], end = rowptr_s[s + 1];
    if (beg == end) return;
    int eg = lane >> 4, c16 = lane & 15;
    int cbase = c16 * 8;
    float xr[NB][8];
    #pragma unroll
    for (int b = 0; b < NB; b++)
        #pragma unroll
        for (int i = 0; i < 8; i++) xr[b][i] = 0.f;
    if (cbase < HID) {
        #pragma unroll
        for (int b = 0; b < NB; b++) {
            const ushort_t* base = xbh + (size_t)s * OUTW + b * HID + cbase;
            ushort4 v0 = *(const ushort4*)base;       // 8B aligned
            xr[b][0] = bf2f(v0.x); xr[b][1] = bf2f(v0.y);
            xr[b][2] = bf2f(v0.z); xr[b][3] = bf2f(v0.w);
            if (cbase + 8 <= HID) {
                ushort4 v1 = *(const ushort4*)(base + 4);
                xr[b][4] = bf2f(v1.x); xr[b][5] = bf2f(v1.y);
                xr[b][6] = bf2f(v1.z); xr[b][7] = bf2f(v1.w);
            }
        }
    }
    for (int w0 = beg; w0 < end; w0 += 64) {
        // one coalesced key load covers the next 64 edges (16 quads)
        int kw = (w0 + lane < end) ? skey_s[w0 + lane] : 0;
        int wend = w0 + 64 < end ? w0 + 64 : end;
        for (int p0 = w0; p0 < wend; p0 += 4) {
            int j = p0 - w0 + eg;              // < 64 always
            int rt = __shfl(kw, j) & 63;       // zero memory ops in chain
            int p = p0 + eg;
            const float* cr = &scomp[rt * NB];
            float z[8] = {};
            #pragma unroll
            for (int b = 0; b < NB; b++) {
                float cb = cr[b];
                #pragma unroll
                for (int i = 0; i < 8; i++) z[i] = fmaf(cb, xr[b][i], z[i]);
            }
            ushort8 zz;
            #pragma unroll
            for (int i = 0; i < 8; i++) zz[i] = f2bf_rne(z[i]);
            // BUGFIX r4->r5: cbase 104/112/120 would overrun the 104-ushort
            // row into the NEXT edge's channels (race) -- guard cbase < ZW.
            if (p < end && cbase < ZW)
                *(ushort8*)&Z[(size_t)p * ZW + cbase] = zz;   // 16B, coalesced
        }
    }
}

// ==== dst-major: online softmax + paired-edge Z gather + bias; comp in LDS ====
// q/k now come as per-(n,b) partial PAIRS from the gemm epilogue: value =
// xp[n*16+b*2] + xp[n*16+b*2+1].
// WB=1: write relu'd bf16 into padded layer-2 A buffer (hb) instead of f32 h.
template<int WB>
__global__ __launch_bounds__(256) void msg_soft(
        const int* __restrict__ rowptr, const int* __restrict__ skey,
        const int* __restrict__ zidx,
        const float* __restrict__ comp, const ushort_t* __restrict__ Z,
        const float* __restrict__ xbqp, const float* __restrict__ xbkp,
        const float* __restrict__ bias, float* __restrict__ h,
        ushort_t* __restrict__ hb) {
    __shared__ float scomp[R_REL * NB];   // 1.6 KB
    int tid = threadIdx.x;
    for (int i = tid; i < R_REL * NB; i += 256) scomp[i] = comp[i];
    __syncthreads();
    int wave = tid >> 6, lane = tid & 63;
    int d = blockIdx.x * 4 + wave;
    if (d >= N_NODES) return;
    int beg = rowptr[d], end = rowptr[d + 1];

    const float* qp = &xbqp[(size_t)d * 16];
    float4 qa = *(const float4*)qp,       qb = *(const float4*)(qp + 4);
    float4 qc = *(const float4*)(qp + 8), qe = *(const float4*)(qp + 12);
    float4 qd0 = { qa.x + qa.y, qa.z + qa.w, qb.x + qb.y, qb.z + qb.w };
    float4 qd1 = { qc.x + qc.y, qc.z + qc.w, qe.x + qe.y, qe.z + qe.w };

    int l5 = lane & 31;
    bool act = l5 < 25;
    int oc = l5 * 4;                  // channel base (4 channels per lane)
    f32x4 acc = {0.f, 0.f, 0.f, 0.f};
    float m = -1e30f, l = 0.f;

    for (int c0 = beg; c0 < end; c0 += 64) {
        int p = c0 + lane;
        bool valid = p < end;
        float a = -1e30f;
        int zi = 0;
        if (valid) {
            int key = skey[p];
            zi = zidx[p];
            int s = key >> 6, rt = key & 63;
            const float4 c0v = *(const float4*)&scomp[rt * NB];
            const float4 c1v = *(const float4*)&scomp[rt * NB + 4];
            const float* kp = &xbkp[(size_t)s * 16];
            float4 ka = *(const float4*)kp,       kb = *(const float4*)(kp + 4);
            float4 kc = *(const float4*)(kp + 8), ke = *(const float4*)(kp + 12);
            float4 k0v = { ka.x + ka.y, ka.z + ka.w, kb.x + kb.y, kb.z + kb.w };
            float4 k1v = { kc.x + kc.y, kc.z + kc.w, ke.x + ke.y, ke.z + ke.w };
            float qi = c0v.x*qd0.x + c0v.y*qd0.y + c0v.z*qd0.z + c0v.w*qd0.w
                     + c1v.x*qd1.x + c1v.y*qd1.y + c1v.z*qd1.z + c1v.w*qd1.w;
            float kj = c0v.x*k0v.x + c0v.y*k0v.y + c0v.z*k0v.z + c0v.w*k0v.w
                     + c1v.x*k1v.x + c1v.y*k1v.y + c1v.z*k1v.z + c1v.w*k1v.w;
            float av = qi + kj;
            a = av > 0.f ? av : 0.2f * av;  // leaky_relu 0.2
        }
        float cm = a;
        #pragma unroll
        for (int off = 32; off; off >>= 1) cm = fmaxf(cm, __shfl_xor(cm, off));
        float M = fmaxf(m, cm);
        float scale = __expf(m - M);
        acc *= scale; l *= scale; m = M;
        float wgt = valid ? __expf(a - M) : 0.f;
        float cs = wgt;
        #pragma unroll
        for (int off = 32; off; off >>= 1) cs += __shfl_xor(cs, off);
        l += cs;
        int cnt = end - c0; if (cnt > 64) cnt = 64;
        for (int j = 0; j < cnt; j += 2) {
            int jj = j + (lane >> 5);         // even half: j, odd half: j+1
            float wj = __shfl(wgt, jj);       // invalid -> 0
            int   zj = __shfl(zi, jj);
            if (act) {
                ushort4 zz = *(const ushort4*)&Z[(size_t)zj * ZW + oc];
                acc.x = fmaf(wj, bf2f(zz.x), acc.x);
                acc.y = fmaf(wj, bf2f(zz.y), acc.y);
                acc.z = fmaf(wj, bf2f(zz.z), acc.z);
                acc.w = fmaf(wj, bf2f(zz.w), acc.w);
            }
        }
    }
    // combine even/odd-edge halves: lane ℓ (<25) += lane ℓ+32
    #pragma unroll
    for (int i = 0; i < 4; i++) acc[i] += __shfl_xor(acc[i], 32);
    if (lane < 25) {
        float inv = 1.f / (l + 1e-16f);
        float4 r;
        r.x = bias[oc]     + acc.x * inv;
        r.y = bias[oc + 1] + acc.y * inv;
        r.z = bias[oc + 2] + acc.z * inv;
        r.w = bias[oc + 3] + acc.w * inv;
        if (WB) {
            ushort4 o;
            o.x = f2bf_rne(fmaxf(r.x, 0.f));
            o.y = f2bf_rne(fmaxf(r.y, 0.f));
            o.z = f2bf_rne(fmaxf(r.z, 0.f));
            o.w = f2bf_rne(fmaxf(r.w, 0.f));
            *(ushort4*)&hb[(size_t)d * KP2 + oc] = o;   // 8B aligned
        } else {
            *(float4*)&h[(size_t)d * HID + oc] = r;     // 16B aligned
        }
    }
}

// ---- pooled = mean(relu(h2[qidx])); out = pooled @ Wl^T + bl ----
__global__ __launch_bounds__(128) void head_kernel(
        const float* __restrict__ h2, const int* __restrict__ qidx,
        const float* __restrict__ Wl, const float* __restrict__ bl,
        float* __restrict__ out) {
    __shared__ float pooled[HID];
    int tid = threadIdx.x;
    if (tid < HID) {
        float s = 0.f;
        for (int i = 0; i < NQ; i++)
            s += fmaxf(h2[(size_t)qidx[i] * HID + tid], 0.f);
        pooled[tid] = s * (1.0f / NQ);
    }
    __syncthreads();
    if (tid < CLS) {
        float s = bl[tid];
        for (int o = 0; o < HID; o++) s = fmaf(pooled[o], Wl[tid * HID + o], s);
        out[tid] = s;
    }
}

extern "C" void kernel_launch(void* const* d_in, const int* in_sizes, int n_in,
                              void* d_out, int out_size, void* d_ws, size_t ws_size,
                              hipStream_t stream) {
    const float* x      = (const float*)d_in[0];
    const int*   ei     = (const int*)  d_in[1];
    const int*   et     = (const int*)  d_in[2];
    const int*   qidx   = (const int*)  d_in[3];
    const float* comp1  = (const float*)d_in[4];
    const float* basis1 = (const float*)d_in[5];
    const float* q1     = (const float*)d_in[6];
    const float* k1     = (const float*)d_in[7];
    const float* b1     = (const float*)d_in[8];
    const float* comp2  = (const float*)d_in[9];
    const float* basis2 = (const float*)d_in[10];
    const float* q2     = (const float*)d_in[11];
    const float* k2     = (const float*)d_in[12];
    const float* b2     = (const float*)d_in[13];
    const float* Wl     = (const float*)d_in[14];
    const float* bl     = (const float*)d_in[15];
    float* out = (float*)d_out;

    char* w = (char*)d_ws;
    size_t off = 0;
    auto alloc = [&](size_t nbytes) {
        void* p = (void*)(w + off);
        off += ((nbytes + 255) / 256) * 256;
        return p;
    };
    ushort_t* xbh    = (ushort_t*)alloc((size_t)N_NODES * OUTW * 2); // 32 MB
    ushort_t* Z      = (ushort_t*)alloc((size_t)E_EDGES * ZW * 2);   // 66.6 MB
    float*    h2     = (float*)alloc((size_t)N_NODES * HID * 4);     // 8 MB
    ushort_t* Bt1    = (ushort_t*)alloc((size_t)OUTW * KP1 * 2);     // 512 KB
    ushort_t* Bt2    = (ushort_t*)alloc((size_t)OUTW * KP2 * 2);     // 205 KB
    ushort_t* xbA    = (ushort_t*)alloc((size_t)MPAD * KP1 * 2);     // 12.9 MB
    ushort_t* hbA    = (ushort_t*)alloc((size_t)MPAD * KP2 * 2);     // 5.2 MB
    float*    xbqp   = (float*)alloc((size_t)MPAD * 16 * 4);         // 1.3 MB
    float*    xbkp   = (float*)alloc((size_t)MPAD * 16 * 4);         // 1.3 MB
    int*      deg_d  = (int*)alloc(N_NODES * 4);
    int*      deg_s  = (int*)alloc(N_NODES * 4);
    int*      rp_d   = (int*)alloc((N_NODES + 1) * 4);
    int*      rp_s   = (int*)alloc((N_NODES + 1) * 4);
    int*      cur_d  = (int*)alloc(N_NODES * 4);
    int*      cur_s  = (int*)alloc(N_NODES * 4);
    int*      bsum_d = (int*)alloc(SCAN_BLKS * 4);
    int*      bsum_s = (int*)alloc(SCAN_BLKS * 4);
    int*      skey   = (int*)alloc(E_EDGES * 4);
    int*      skey_s = (int*)alloc(E_EDGES * 4);
    int*      zidx   = (int*)alloc(E_EDGES * 4);

    // ---- fused preprocessing + CSR build ----
    prep_kernel<<<(PREP_TOT + 255) / 256, 256, 0, stream>>>(
        basis1, Bt1, basis2, Bt2, x, xbA, hbA, deg_d, deg_s);
    hist2_kernel<<<(E_EDGES + 255) / 256, 256, 0, stream>>>(ei, deg_d, deg_s);
    scan1_both<<<2 * SCAN_BLKS, 256, 0, stream>>>(deg_d, rp_d, bsum_d, deg_s, rp_s, bsum_s);
    scan2_both<<<2, 128, 0, stream>>>(bsum_d, rp_d, bsum_s, rp_s);
    scan3_both<<<2 * SCAN_BLKS, 256, 0, stream>>>(rp_d, bsum_d, cur_d, rp_s, bsum_s, cur_s);
    scatter_both<<<(E_EDGES + 255) / 256, 256, 0, stream>>>(ei, et, cur_d, cur_s, skey, skey_s, zidx);

    // ---- layer 1 (msg_soft writes relu'd bf16 straight into hbA) ----
    gemm_mfma<KP1><<<10 * GEMM_RG, 512, 0, stream>>>(xbA, Bt1, xbh, N_NODES, q1, k1, xbqp, xbkp);
    compute_z<<<(N_NODES + 3) / 4, 256, 0, stream>>>(rp_s, skey_s, comp1, xbh, Z);
    msg_soft<1><<<(N_NODES + 3) / 4, 256, 0, stream>>>(rp_d, skey, zidx, comp1, Z, xbqp, xbkp, b1, (float*)nullptr, hbA);

    // ---- layer 2 ----
    gemm_mfma<KP2><<<10 * GEMM_RG, 512, 0, stream>>>(hbA, Bt2, xbh, N_NODES, q2, k2, xbqp, xbkp);
    compute_z<<<(N_NODES + 3) / 4, 256, 0, stream>>>(rp_s, skey_s, comp2, xbh, Z);
    msg_soft<0><<<(N_NODES + 3) / 4, 256, 0, stream>>>(rp_d, skey, zidx, comp2, Z, xbqp, xbkp, b2, h2, (ushort_t*)nullptr);

    head_kernel<<<1, 128, 0, stream>>>(h2, qidx, Wl, bl, out);
}

// Round 6
// 394.840 us; speedup vs baseline: 1.2235x; 1.2235x over previous
//
#include <hip/hip_runtime.h>
#include <math.h>

#define N_NODES 20000
#define E_EDGES 320000
#define IN_CH   300
#define HID     100
#define R_REL   50
#define NB      8
#define CLS     3
#define NQ      64
#define OUTW    800   // NB * HID
#define ZW      104   // Z row stride (ushorts): 208-B rows (16B-aligned), exact fit
#define KP1     320
#define KP2     128
#define MPAD    20224 // 79 * 256 (row-chunk padded M for A bf16 buffers)
#define NPAIR   79    // MPAD / 256
#define GEMM_RG 48    // row-groups; grid = 10 col-blocks * 48 = 480 blocks
#define SCAN_BLKS ((N_NODES + 255) / 256)   // 79

typedef unsigned short ushort_t;
typedef __attribute__((ext_vector_type(8))) short     short8;
typedef __attribute__((ext_vector_type(8))) unsigned short ushort8;
typedef __attribute__((ext_vector_type(4))) float     f32x4;
typedef __attribute__((ext_vector_type(2))) float     f32x2;

__device__ __forceinline__ ushort_t f2bf_rne(float f) {   // round-nearest-even
    unsigned u = __float_as_uint(f);
    unsigned r = (u + 0x7fffu + ((u >> 16) & 1u)) >> 16;
    return (ushort_t)r;
}
__device__ __forceinline__ float bf2f(ushort_t u) {
    return __uint_as_float((unsigned)u << 16);
}

// ============================ CSR build =================================
__global__ __launch_bounds__(256) void hist2_kernel(
        const int* __restrict__ ei, int* __restrict__ dd,
        int* __restrict__ ds) {
    int e = blockIdx.x * 256 + threadIdx.x;
    if (e < E_EDGES) {
        atomicAdd(&dd[ei[E_EDGES + e]], 1);
        atomicAdd(&ds[ei[e]], 1);
    }
}

// dual-set scans: blockIdx selects (deg_d...) or (deg_s...) set
__global__ __launch_bounds__(256) void scan1_both(
        const int* __restrict__ deg_d, int* __restrict__ rp_d, int* __restrict__ bsum_d,
        const int* __restrict__ deg_s, int* __restrict__ rp_s, int* __restrict__ bsum_s) {
    int set = blockIdx.x / SCAN_BLKS, blk = blockIdx.x % SCAN_BLKS;
    const int* deg = set ? deg_s : deg_d;
    int* rowptr    = set ? rp_s  : rp_d;
    int* bsum      = set ? bsum_s : bsum_d;
    __shared__ int s[256];
    int tid = threadIdx.x;
    int idx = blk * 256 + tid;
    int v = (idx < N_NODES) ? deg[idx] : 0;
    s[tid] = v; __syncthreads();
    #pragma unroll
    for (int off = 1; off < 256; off <<= 1) {
        int t = (tid >= off) ? s[tid - off] : 0;
        __syncthreads();
        s[tid] += t;
        __syncthreads();
    }
    if (idx < N_NODES) rowptr[idx] = s[tid] - v;   // exclusive
    if (tid == 255) bsum[blk] = s[255];
}

__global__ __launch_bounds__(128) void scan2_both(
        int* __restrict__ bsum_d, int* __restrict__ rp_d,
        int* __restrict__ bsum_s, int* __restrict__ rp_s) {
    int* bsum   = blockIdx.x ? bsum_s : bsum_d;
    int* rowptr = blockIdx.x ? rp_s   : rp_d;
    __shared__ int s[128];
    int tid = threadIdx.x;
    int v = (tid < SCAN_BLKS) ? bsum[tid] : 0;
    s[tid] = v; __syncthreads();
    #pragma unroll
    for (int off = 1; off < 128; off <<= 1) {
        int t = (tid >= off) ? s[tid - off] : 0;
        __syncthreads();
        s[tid] += t;
        __syncthreads();
    }
    if (tid < SCAN_BLKS) bsum[tid] = s[tid] - v;   // exclusive
    if (tid == 0) rowptr[N_NODES] = E_EDGES;
}

__global__ __launch_bounds__(256) void scan3_both(
        int* __restrict__ rp_d, const int* __restrict__ bsum_d, int* __restrict__ cur_d,
        int* __restrict__ rp_s, const int* __restrict__ bsum_s, int* __restrict__ cur_s) {
    int set = blockIdx.x / SCAN_BLKS, blk = blockIdx.x % SCAN_BLKS;
    int* rowptr      = set ? rp_s   : rp_d;
    const int* bsum  = set ? bsum_s : bsum_d;
    int* cursor      = set ? cur_s  : cur_d;
    int idx = blk * 256 + threadIdx.x;
    if (idx < N_NODES) {
        int v = rowptr[idx] + bsum[blk];
        rowptr[idx] = v;
        cursor[idx] = v;
    }
}

// fused scatter: dst-CSR key (src,rel), src-CSR key (rel), and zidx map
__global__ __launch_bounds__(256) void scatter_both(
        const int* __restrict__ ei, const int* __restrict__ et,
        int* __restrict__ cur_d, int* __restrict__ cur_s,
        int* __restrict__ skey, int* __restrict__ skey_s,
        int* __restrict__ zidx) {
    int e = blockIdx.x * 256 + threadIdx.x;
    if (e >= E_EDGES) return;
    int s = ei[e], d = ei[E_EDGES + e], rt = et[e];
    int p = atomicAdd(&cur_d[d], 1);
    skey[p] = (s << 6) | rt;                 // dst-order: (src, rel)
    int qp = atomicAdd(&cur_s[s], 1);
    skey_s[qp] = rt;                         // src-order: rel only
    zidx[p] = qp;                            // dst-slot -> Z row (src-slot)
}

// ==== fused preprocessing: Bt1, Bt2, cvt_pad(x), hbA-zero, deg-zero ====
// One dispatch replaces 4: fewer launch gaps, all regions independent.
#define PREP_N1 (OUTW * KP1)                 // Bt1
#define PREP_N2 (OUTW * KP2)                 // Bt2
#define PREP_NC (MPAD * (KP1 / 8))           // cvt_pad x (ushort8 chunks)
#define PREP_NZ (MPAD * (KP2 / 8))           // hbA zero (ushort8 chunks)
#define PREP_TOT (PREP_N1 + PREP_N2 + PREP_NC + PREP_NZ + N_NODES)
__global__ __launch_bounds__(256) void prep_kernel(
        const float* __restrict__ basis1, ushort_t* __restrict__ Bt1,
        const float* __restrict__ basis2, ushort_t* __restrict__ Bt2,
        const float* __restrict__ x, ushort_t* __restrict__ xbA,
        ushort_t* __restrict__ hbA,
        int* __restrict__ dd, int* __restrict__ ds) {
    int idx = blockIdx.x * 256 + threadIdx.x;
    if (idx < PREP_N1) {
        int n = idx / KP1, k = idx - n * KP1;
        int b = n / HID, o = n - b * HID;
        float v = (k < IN_CH) ? basis1[((size_t)b * IN_CH + k) * HID + o] : 0.f;
        Bt1[idx] = f2bf_rne(v);
        return;
    }
    idx -= PREP_N1;
    if (idx < PREP_N2) {
        int n = idx / KP2, k = idx - n * KP2;
        int b = n / HID, o = n - b * HID;
        float v = (k < HID) ? basis2[((size_t)b * HID + k) * HID + o] : 0.f;
        Bt2[idx] = f2bf_rne(v);
        return;
    }
    idx -= PREP_N2;
    if (idx < PREP_NC) {                       // x -> bf16 padded
        constexpr int CH = KP1 / 8;
        int n = idx / CH, c = idx - n * CH;
        int k = c * 8;
        float v[8];
        if (n < N_NODES && k + 8 <= IN_CH) {
            float4 f0 = *(const float4*)&x[(size_t)n * IN_CH + k];
            float4 f1 = *(const float4*)&x[(size_t)n * IN_CH + k + 4];
            v[0]=f0.x; v[1]=f0.y; v[2]=f0.z; v[3]=f0.w;
            v[4]=f1.x; v[5]=f1.y; v[6]=f1.z; v[7]=f1.w;
        } else {
            #pragma unroll
            for (int i = 0; i < 8; i++)
                v[i] = (n < N_NODES && k + i < IN_CH) ? x[(size_t)n * IN_CH + k + i] : 0.f;
        }
        ushort8 hv;
        #pragma unroll
        for (int i = 0; i < 8; i++) hv[i] = f2bf_rne(v[i]);
        *(ushort8*)&xbA[(size_t)n * KP1 + k] = hv;
        return;
    }
    idx -= PREP_NC;
    if (idx < PREP_NZ) {                       // hbA zero (pads must be 0)
        ushort8 z = {};
        *(ushort8*)&hbA[(size_t)idx * 8] = z;
        return;
    }
    idx -= PREP_NZ;
    if (idx < N_NODES) { dd[idx] = 0; ds[idx] = 0; }
}

// ---- MFMA GEMM + fused q/k partial dots ----
// xbh[M,800](bf16) = Ab[M,KP](bf16) * B[KP,800]
// 480 blocks = 10 col-blocks (80 cols) x 48 row-groups, 512 threads.
// XCD-affine mapping (FETCH ~= A read once, verified r3).
// qk fusion: xbq[n,b] = sum_c xbh[n,b*100+c] q[c]; (b, part) -> (cb, slot)
// bijective, partials written WITHOUT atomics; msg_soft sums the pair.
// __launch_bounds__(512, 2): MUST stay 2 — r5's (512,4) capped VGPR at 64,
// spilling the 80-VGPR A-frags + 40-VGPR accs to scratch (FETCH 16->150 MB,
// WRITE 48->209 MB, 47->112+ us). LDS (52.5 KB) caps residency anyway.
template<int KP>
__global__ __launch_bounds__(512, 2) void gemm_mfma(
        const ushort_t* __restrict__ Ab, const ushort_t* __restrict__ Bt,
        ushort_t* __restrict__ xbh, int M,
        const float* __restrict__ qw, const float* __restrict__ kw,
        float* __restrict__ xq, float* __restrict__ xk) {
    constexpr int KSTEPS = KP / 32;           // 10 (layer1) / 4 (layer2)
    constexpr int SW = KP + 8;                // LDS col stride (ushorts)
    constexpr int CH = KP / 8;
    __shared__ ushort_t Bs[80 * SW];          // 52.5 KB (L1) / 21.3 KB (L2)
    __shared__ float sqk[2 * HID];            // q then k (800 B)
    int tid = threadIdx.x, lane = tid & 63, wave = tid >> 6;
    int ml = lane & 15, quad = lane >> 4;
    // XCD-affine de-swizzle: b = (rg&7) + 8*cb + 80*(rg>>3)
    int b = blockIdx.x;
    int xcd = b & 7, qq = b >> 3;
    int cb = qq % 10;                         // 10 col blocks of 80
    int rg = xcd + 8 * (qq / 10);             // 0..47
    int col0 = cb * 80;

    // ---- stage B tile once (coalesced 16B chunks) + q/k vectors ----
    if (tid < 2 * HID) sqk[tid] = (tid < HID) ? qw[tid] : kw[tid - HID];
    for (int t = tid; t < 80 * CH; t += 512) {
        int c = t / CH, ch = t - c * CH;
        *(ushort8*)&Bs[c * SW + ch * 8] =
            *(const ushort8*)&Bt[(size_t)(col0 + c) * KP + ch * 8];
    }
    __syncthreads();                          // the ONLY barrier

    const ushort_t* bb = &Bs[(size_t)ml * SW + quad * 8];

    // per-lane qk-partial constants for this col-block
    int bLo = col0 / 100, bHi = (col0 + 79) / 100;
    int split = (bHi != bLo) ? bHi * 100 : (col0 + 160);   // unreachable if 1 slice
    int slotLo = ((bLo * 100) / 80 == cb) ? 0 : 1;
    int slotHi = ((bHi * 100) / 80 == cb) ? 0 : 1;
    float qv[5], kv[5];
    int himask = 0;
    #pragma unroll
    for (int nt = 0; nt < 5; nt++) {
        int c = col0 + nt * 16 + ml;
        int cm = c % 100;
        qv[nt] = sqk[cm]; kv[nt] = sqk[100 + cm];
        if (c >= split) himask |= 1 << nt;
    }

    for (int g = rg; g < NPAIR; g += GEMM_RG) {
        int rbase = g * 256 + wave * 32;      // this wave's 32 rows
        const ushort_t* ar0 = Ab + (size_t)(rbase + ml) * KP + quad * 8;
        const ushort_t* ar1 = ar0 + (size_t)16 * KP;
        short8 a0[KSTEPS], a1[KSTEPS];
        #pragma unroll
        for (int ks = 0; ks < KSTEPS; ks++) {
            a0[ks] = *(const short8*)(ar0 + ks * 32);
            a1[ks] = *(const short8*)(ar1 + ks * 32);
        }
        f32x4 acc0[5] = {}, acc1[5] = {};
        #pragma unroll
        for (int ks = 0; ks < KSTEPS; ks++) {
            short8 bf[5];
            #pragma unroll
            for (int nt = 0; nt < 5; nt++)
                bf[nt] = *(const short8*)(bb + nt * 16 * SW + ks * 32);
            #pragma unroll
            for (int nt = 0; nt < 5; nt++) {
                acc0[nt] = __builtin_amdgcn_mfma_f32_16x16x32_bf16(
                               a0[ks], bf[nt], acc0[nt], 0, 0, 0);
                acc1[nt] = __builtin_amdgcn_mfma_f32_16x16x32_bf16(
                               a1[ks], bf[nt], acc1[nt], 0, 0, 0);
            }
        }
        // epilogue (C layout: row = quad*4 + r, col = nt*16 + ml)
        #pragma unroll
        for (int nt = 0; nt < 5; nt++) {
            #pragma unroll
            for (int r = 0; r < 4; r++) {
                int g0 = rbase + quad * 4 + r;
                if (g0 < M)
                    xbh[(size_t)g0 * OUTW + col0 + nt * 16 + ml] =
                        f2bf_rne(acc0[nt][r]);
                int g1 = g0 + 16;
                if (g1 < M)
                    xbh[(size_t)g1 * OUTW + col0 + nt * 16 + ml] =
                        f2bf_rne(acc1[nt][r]);
            }
        }
        // fused q/k partial dots: reduce over ml lanes, write per (row,b,slot)
        #pragma unroll
        for (int r = 0; r < 4; r++) {
            float pqL = 0, pqH = 0, pkL = 0, pkH = 0;   // acc0 rows
            float sqL = 0, sqH = 0, skL = 0, skH = 0;   // acc1 rows
            #pragma unroll
            for (int nt = 0; nt < 5; nt++) {
                float v0 = acc0[nt][r], v1 = acc1[nt][r];
                if (himask & (1 << nt)) {
                    pqH = fmaf(v0, qv[nt], pqH); pkH = fmaf(v0, kv[nt], pkH);
                    sqH = fmaf(v1, qv[nt], sqH); skH = fmaf(v1, kv[nt], skH);
                } else {
                    pqL = fmaf(v0, qv[nt], pqL); pkL = fmaf(v0, kv[nt], pkL);
                    sqL = fmaf(v1, qv[nt], sqL); skL = fmaf(v1, kv[nt], skL);
                }
            }
            #pragma unroll
            for (int off = 1; off < 16; off <<= 1) {
                pqL += __shfl_xor(pqL, off); pqH += __shfl_xor(pqH, off);
                pkL += __shfl_xor(pkL, off); pkH += __shfl_xor(pkH, off);
                sqL += __shfl_xor(sqL, off); sqH += __shfl_xor(sqH, off);
                skL += __shfl_xor(skL, off); skH += __shfl_xor(skH, off);
            }
            if (ml == 0) {
                int r0 = rbase + quad * 4 + r, r1 = r0 + 16;
                int iLo0 = r0 * 16 + bLo * 2 + slotLo;
                int iLo1 = r1 * 16 + bLo * 2 + slotLo;
                xq[iLo0] = pqL; xk[iLo0] = pkL;
                xq[iLo1] = sqL; xk[iLo1] = skL;
                if (bHi != bLo) {
                    int iHi0 = r0 * 16 + bHi * 2 + slotHi;
                    int iHi1 = r1 * 16 + bHi * 2 + slotHi;
                    xq[iHi0] = pqH; xk[iHi0] = pkH;
                    xq[iHi1] = sqH; xk[iHi1] = skH;
                }
            }
        }
    }
}

// ==== src-major, batched-4 Z rows; comp in LDS; keys via register window ====
// lane = eg*16 + c16; covers channels [8*c16, 8*c16+8) of edge p0+eg.
__global__ __launch_bounds__(256) void compute_z(
        const int* __restrict__ rowptr_s, const int* __restrict__ skey_s,
        const float* __restrict__ comp, const ushort_t* __restrict__ xbh,
        ushort_t* __restrict__ Z) {
    __shared__ float scomp[R_REL * NB];   // 1.6 KB
    int tid = threadIdx.x;
    for (int i = tid; i < R_REL * NB; i += 256) scomp[i] = comp[i];
    __syncthreads();
    int wave = tid >> 6, lane = tid & 63;
    int s = blockIdx.x * 4 + wave;
    if (s >= N_NODES) return;
    int beg = rowptr_s[s], end = rowptr_s[s + 1];
    if (beg == end) return;
    int eg = lane >> 4, c16 = lane & 15;
    int cbase = c16 * 8;
    float xr[NB][8];
    #pragma unroll
    for (int b = 0; b < NB; b++)
        #pragma unroll
        for (int i = 0; i < 8; i++) xr[b][i] = 0.f;
    if (cbase < HID) {
        #pragma unroll
        for (int b = 0; b < NB; b++) {
            const ushort_t* base = xbh + (size_t)s * OUTW + b * HID + cbase;
            ushort4 v0 = *(const ushort4*)base;       // 8B aligned
            xr[b][0] = bf2f(v0.x); xr[b][1] = bf2f(v0.y);
            xr[b][2] = bf2f(v0.z); xr[b][3] = bf2f(v0.w);
            if (cbase + 8 <= HID) {
                ushort4 v1 = *(const ushort4*)(base + 4);
                xr[b][4] = bf2f(v1.x); xr[b][5] = bf2f(v1.y);
                xr[b][6] = bf2f(v1.z); xr[b][7] = bf2f(v1.w);
            }
        }
    }
    for (int w0 = beg; w0 < end; w0 += 64) {
        // one coalesced key load covers the next 64 edges (16 quads)
        int kw = (w0 + lane < end) ? skey_s[w0 + lane] : 0;
        int wend = w0 + 64 < end ? w0 + 64 : end;
        for (int p0 = w0; p0 < wend; p0 += 4) {
            int j = p0 - w0 + eg;              // < 64 always
            int rt = __shfl(kw, j) & 63;       // zero memory ops in chain
            int p = p0 + eg;
            const float* cr = &scomp[rt * NB];
            float z[8] = {};
            #pragma unroll
            for (int b = 0; b < NB; b++) {
                float cb = cr[b];
                #pragma unroll
                for (int i = 0; i < 8; i++) z[i] = fmaf(cb, xr[b][i], z[i]);
            }
            ushort8 zz;
            #pragma unroll
            for (int i = 0; i < 8; i++) zz[i] = f2bf_rne(z[i]);
            // guard: cbase 104/112/120 would overrun the 104-ushort row
            if (p < end && cbase < ZW)
                *(ushort8*)&Z[(size_t)p * ZW + cbase] = zz;   // 16B, coalesced
        }
    }
}

// ==== dst-major: online softmax + paired-edge Z gather + bias; comp in LDS ====
// q/k come as per-(n,b) partial PAIRS from the gemm epilogue: value =
// xp[n*16+b*2] + xp[n*16+b*2+1].
// WB=1: write relu'd bf16 into padded layer-2 A buffer (hb) instead of f32 h.
template<int WB>
__global__ __launch_bounds__(256) void msg_soft(
        const int* __restrict__ rowptr, const int* __restrict__ skey,
        const int* __restrict__ zidx,
        const float* __restrict__ comp, const ushort_t* __restrict__ Z,
        const float* __restrict__ xbqp, const float* __restrict__ xbkp,
        const float* __restrict__ bias, float* __restrict__ h,
        ushort_t* __restrict__ hb) {
    __shared__ float scomp[R_REL * NB];   // 1.6 KB
    int tid = threadIdx.x;
    for (int i = tid; i < R_REL * NB; i += 256) scomp[i] = comp[i];
    __syncthreads();
    int wave = tid >> 6, lane = tid & 63;
    int d = blockIdx.x * 4 + wave;
    if (d >= N_NODES) return;
    int beg = rowptr[d], end = rowptr[d + 1];

    const float* qp = &xbqp[(size_t)d * 16];
    float4 qa = *(const float4*)qp,       qb = *(const float4*)(qp + 4);
    float4 qc = *(const float4*)(qp + 8), qe = *(const float4*)(qp + 12);
    float4 qd0 = { qa.x + qa.y, qa.z + qa.w, qb.x + qb.y, qb.z + qb.w };
    float4 qd1 = { qc.x + qc.y, qc.z + qc.w, qe.x + qe.y, qe.z + qe.w };

    int l5 = lane & 31;
    bool act = l5 < 25;
    int oc = l5 * 4;                  // channel base (4 channels per lane)
    f32x4 acc = {0.f, 0.f, 0.f, 0.f};
    float m = -1e30f, l = 0.f;

    for (int c0 = beg; c0 < end; c0 += 64) {
        int p = c0 + lane;
        bool valid = p < end;
        float a = -1e30f;
        int zi = 0;
        if (valid) {
            int key = skey[p];
            zi = zidx[p];
            int s = key >> 6, rt = key & 63;
            const float4 c0v = *(const float4*)&scomp[rt * NB];
            const float4 c1v = *(const float4*)&scomp[rt * NB + 4];
            const float* kp = &xbkp[(size_t)s * 16];
            float4 ka = *(const float4*)kp,       kb = *(const float4*)(kp + 4);
            float4 kc = *(const float4*)(kp + 8), ke = *(const float4*)(kp + 12);
            float4 k0v = { ka.x + ka.y, ka.z + ka.w, kb.x + kb.y, kb.z + kb.w };
            float4 k1v = { kc.x + kc.y, kc.z + kc.w, ke.x + ke.y, ke.z + ke.w };
            float qi = c0v.x*qd0.x + c0v.y*qd0.y + c0v.z*qd0.z + c0v.w*qd0.w
                     + c1v.x*qd1.x + c1v.y*qd1.y + c1v.z*qd1.z + c1v.w*qd1.w;
            float kj = c0v.x*k0v.x + c0v.y*k0v.y + c0v.z*k0v.z + c0v.w*k0v.w
                     + c1v.x*k1v.x + c1v.y*k1v.y + c1v.z*k1v.z + c1v.w*k1v.w;
            float av = qi + kj;
            a = av > 0.f ? av : 0.2f * av;  // leaky_relu 0.2
        }
        float cm = a;
        #pragma unroll
        for (int off = 32; off; off >>= 1) cm = fmaxf(cm, __shfl_xor(cm, off));
        float M = fmaxf(m, cm);
        float scale = __expf(m - M);
        acc *= scale; l *= scale; m = M;
        float wgt = valid ? __expf(a - M) : 0.f;
        float cs = wgt;
        #pragma unroll
        for (int off = 32; off; off >>= 1) cs += __shfl_xor(cs, off);
        l += cs;
        int cnt = end - c0; if (cnt > 64) cnt = 64;
        for (int j = 0; j < cnt; j += 2) {
            int jj = j + (lane >> 5);         // even half: j, odd half: j+1
            float wj = __shfl(wgt, jj);       // invalid -> 0
            int   zj = __shfl(zi, jj);
            if (act) {
                ushort4 zz = *(const ushort4*)&Z[(size_t)zj * ZW + oc];
                acc.x = fmaf(wj, bf2f(zz.x), acc.x);
                acc.y = fmaf(wj, bf2f(zz.y), acc.y);
                acc.z = fmaf(wj, bf2f(zz.z), acc.z);
                acc.w = fmaf(wj, bf2f(zz.w), acc.w);
            }
        }
    }
    // combine even/odd-edge halves: lane ℓ (<25) += lane ℓ+32
    #pragma unroll
    for (int i = 0; i < 4; i++) acc[i] += __shfl_xor(acc[i], 32);
    if (lane < 25) {
        float inv = 1.f / (l + 1e-16f);
        float4 r;
        r.x = bias[oc]     + acc.x * inv;
        r.y = bias[oc + 1] + acc.y * inv;
        r.z = bias[oc + 2] + acc.z * inv;
        r.w = bias[oc + 3] + acc.w * inv;
        if (WB) {
            ushort4 o;
            o.x = f2bf_rne(fmaxf(r.x, 0.f));
            o.y = f2bf_rne(fmaxf(r.y, 0.f));
            o.z = f2bf_rne(fmaxf(r.z, 0.f));
            o.w = f2bf_rne(fmaxf(r.w, 0.f));
            *(ushort4*)&hb[(size_t)d * KP2 + oc] = o;   // 8B aligned
        } else {
            *(float4*)&h[(size_t)d * HID + oc] = r;     // 16B aligned
        }
    }
}

// ---- pooled = mean(relu(h2[qidx])); out = pooled @ Wl^T + bl ----
__global__ __launch_bounds__(128) void head_kernel(
        const float* __restrict__ h2, const int* __restrict__ qidx,
        const float* __restrict__ Wl, const float* __restrict__ bl,
        float* __restrict__ out) {
    __shared__ float pooled[HID];
    int tid = threadIdx.x;
    if (tid < HID) {
        float s = 0.f;
        for (int i = 0; i < NQ; i++)
            s += fmaxf(h2[(size_t)qidx[i] * HID + tid], 0.f);
        pooled[tid] = s * (1.0f / NQ);
    }
    __syncthreads();
    if (tid < CLS) {
        float s = bl[tid];
        for (int o = 0; o < HID; o++) s = fmaf(pooled[o], Wl[tid * HID + o], s);
        out[tid] = s;
    }
}

extern "C" void kernel_launch(void* const* d_in, const int* in_sizes, int n_in,
                              void* d_out, int out_size, void* d_ws, size_t ws_size,
                              hipStream_t stream) {
    const float* x      = (const float*)d_in[0];
    const int*   ei     = (const int*)  d_in[1];
    const int*   et     = (const int*)  d_in[2];
    const int*   qidx   = (const int*)  d_in[3];
    const float* comp1  = (const float*)d_in[4];
    const float* basis1 = (const float*)d_in[5];
    const float* q1     = (const float*)d_in[6];
    const float* k1     = (const float*)d_in[7];
    const float* b1     = (const float*)d_in[8];
    const float* comp2  = (const float*)d_in[9];
    const float* basis2 = (const float*)d_in[10];
    const float* q2     = (const float*)d_in[11];
    const float* k2     = (const float*)d_in[12];
    const float* b2     = (const float*)d_in[13];
    const float* Wl     = (const float*)d_in[14];
    const float* bl     = (const float*)d_in[15];
    float* out = (float*)d_out;

    char* w = (char*)d_ws;
    size_t off = 0;
    auto alloc = [&](size_t nbytes) {
        void* p = (void*)(w + off);
        off += ((nbytes + 255) / 256) * 256;
        return p;
    };
    ushort_t* xbh    = (ushort_t*)alloc((size_t)N_NODES * OUTW * 2); // 32 MB
    ushort_t* Z      = (ushort_t*)alloc((size_t)E_EDGES * ZW * 2);   // 66.6 MB
    float*    h2     = (float*)alloc((size_t)N_NODES * HID * 4);     // 8 MB
    ushort_t* Bt1    = (ushort_t*)alloc((size_t)OUTW * KP1 * 2);     // 512 KB
    ushort_t* Bt2    = (ushort_t*)alloc((size_t)OUTW * KP2 * 2);     // 205 KB
    ushort_t* xbA    = (ushort_t*)alloc((size_t)MPAD * KP1 * 2);     // 12.9 MB
    ushort_t* hbA    = (ushort_t*)alloc((size_t)MPAD * KP2 * 2);     // 5.2 MB
    float*    xbqp   = (float*)alloc((size_t)MPAD * 16 * 4);         // 1.3 MB
    float*    xbkp   = (float*)alloc((size_t)MPAD * 16 * 4);         // 1.3 MB
    int*      deg_d  = (int*)alloc(N_NODES * 4);
    int*      deg_s  = (int*)alloc(N_NODES * 4);
    int*      rp_d   = (int*)alloc((N_NODES + 1) * 4);
    int*      rp_s   = (int*)alloc((N_NODES + 1) * 4);
    int*      cur_d  = (int*)alloc(N_NODES * 4);
    int*      cur_s  = (int*)alloc(N_NODES * 4);
    int*      bsum_d = (int*)alloc(SCAN_BLKS * 4);
    int*      bsum_s = (int*)alloc(SCAN_BLKS * 4);
    int*      skey   = (int*)alloc(E_EDGES * 4);
    int*      skey_s = (int*)alloc(E_EDGES * 4);
    int*      zidx   = (int*)alloc(E_EDGES * 4);

    // ---- fused preprocessing + CSR build ----
    prep_kernel<<<(PREP_TOT + 255) / 256, 256, 0, stream>>>(
        basis1, Bt1, basis2, Bt2, x, xbA, hbA, deg_d, deg_s);
    hist2_kernel<<<(E_EDGES + 255) / 256, 256, 0, stream>>>(ei, deg_d, deg_s);
    scan1_both<<<2 * SCAN_BLKS, 256, 0, stream>>>(deg_d, rp_d, bsum_d, deg_s, rp_s, bsum_s);
    scan2_both<<<2, 128, 0, stream>>>(bsum_d, rp_d, bsum_s, rp_s);
    scan3_both<<<2 * SCAN_BLKS, 256, 0, stream>>>(rp_d, bsum_d, cur_d, rp_s, bsum_s, cur_s);
    scatter_both<<<(E_EDGES + 255) / 256, 256, 0, stream>>>(ei, et, cur_d, cur_s, skey, skey_s, zidx);

    // ---- layer 1 (msg_soft writes relu'd bf16 straight into hbA) ----
    gemm_mfma<KP1><<<10 * GEMM_RG, 512, 0, stream>>>(xbA, Bt1, xbh, N_NODES, q1, k1, xbqp, xbkp);
    compute_z<<<(N_NODES + 3) / 4, 256, 0, stream>>>(rp_s, skey_s, comp1, xbh, Z);
    msg_soft<1><<<(N_NODES + 3) / 4, 256, 0, stream>>>(rp_d, skey, zidx, comp1, Z, xbqp, xbkp, b1, (float*)nullptr, hbA);

    // ---- layer 2 ----
    gemm_mfma<KP2><<<10 * GEMM_RG, 512, 0, stream>>>(hbA, Bt2, xbh, N_NODES, q2, k2, xbqp, xbkp);
    compute_z<<<(N_NODES + 3) / 4, 256, 0, stream>>>(rp_s, skey_s, comp2, xbh, Z);
    msg_soft<0><<<(N_NODES + 3) / 4, 256, 0, stream>>>(rp_d, skey, zidx, comp2, Z, xbqp, xbkp, b2, h2, (ushort_t*)nullptr);

    head_kernel<<<1, 128, 0, stream>>>(h2, qidx, Wl, bl, out);
}

// Round 7
// 387.416 us; speedup vs baseline: 1.2470x; 1.0192x over previous
//
#include <hip/hip_runtime.h>
#include <math.h>

#define N_NODES 20000
#define E_EDGES 320000
#define IN_CH   300
#define HID     100
#define R_REL   50
#define NB      8
#define CLS     3
#define NQ      64
#define OUTW    800   // NB * HID
#define ZW      104   // Z row stride (ushorts): 208-B rows (16B-aligned), exact fit
#define KP1     320
#define KP2     128
#define MPAD    20224 // 79 * 256 (row-chunk padded M for A bf16 buffers)
#define NPAIR   79    // MPAD / 256
#define GEMM_RG 48    // row-groups; grid = 10 col-blocks * 48 = 480 blocks
#define NPLANE  20    // qk partial planes: cb*2 + {Lo,Hi}
#define SCAN_BLKS ((N_NODES + 255) / 256)   // 79

typedef unsigned short ushort_t;
typedef __attribute__((ext_vector_type(8))) short     short8;
typedef __attribute__((ext_vector_type(8))) unsigned short ushort8;
typedef __attribute__((ext_vector_type(4))) float     f32x4;
typedef __attribute__((ext_vector_type(2))) float     f32x2;

__device__ __forceinline__ ushort_t f2bf_rne(float f) {   // round-nearest-even
    unsigned u = __float_as_uint(f);
    unsigned r = (u + 0x7fffu + ((u >> 16) & 1u)) >> 16;
    return (ushort_t)r;
}
__device__ __forceinline__ float bf2f(ushort_t u) {
    return __uint_as_float((unsigned)u << 16);
}

// plane-pair table: slice b's two partial planes (enumerated from cb windows)
__device__ const int PAIR_A[8] = {0, 3, 5, 7, 10, 13, 15, 17};
__device__ const int PAIR_B[8] = {2, 4, 6, 8, 12, 14, 16, 18};

// ============================ CSR build =================================
__global__ __launch_bounds__(256) void hist2_kernel(
        const int* __restrict__ ei, int* __restrict__ dd,
        int* __restrict__ ds) {
    int e = blockIdx.x * 256 + threadIdx.x;
    if (e < E_EDGES) {
        atomicAdd(&dd[ei[E_EDGES + e]], 1);
        atomicAdd(&ds[ei[e]], 1);
    }
}

// dual-set scans: blockIdx selects (deg_d...) or (deg_s...) set
__global__ __launch_bounds__(256) void scan1_both(
        const int* __restrict__ deg_d, int* __restrict__ rp_d, int* __restrict__ bsum_d,
        const int* __restrict__ deg_s, int* __restrict__ rp_s, int* __restrict__ bsum_s) {
    int set = blockIdx.x / SCAN_BLKS, blk = blockIdx.x % SCAN_BLKS;
    const int* deg = set ? deg_s : deg_d;
    int* rowptr    = set ? rp_s  : rp_d;
    int* bsum      = set ? bsum_s : bsum_d;
    __shared__ int s[256];
    int tid = threadIdx.x;
    int idx = blk * 256 + tid;
    int v = (idx < N_NODES) ? deg[idx] : 0;
    s[tid] = v; __syncthreads();
    #pragma unroll
    for (int off = 1; off < 256; off <<= 1) {
        int t = (tid >= off) ? s[tid - off] : 0;
        __syncthreads();
        s[tid] += t;
        __syncthreads();
    }
    if (idx < N_NODES) rowptr[idx] = s[tid] - v;   // exclusive
    if (tid == 255) bsum[blk] = s[255];
}

__global__ __launch_bounds__(128) void scan2_both(
        int* __restrict__ bsum_d, int* __restrict__ rp_d,
        int* __restrict__ bsum_s, int* __restrict__ rp_s) {
    int* bsum   = blockIdx.x ? bsum_s : bsum_d;
    int* rowptr = blockIdx.x ? rp_s   : rp_d;
    __shared__ int s[128];
    int tid = threadIdx.x;
    int v = (tid < SCAN_BLKS) ? bsum[tid] : 0;
    s[tid] = v; __syncthreads();
    #pragma unroll
    for (int off = 1; off < 128; off <<= 1) {
        int t = (tid >= off) ? s[tid - off] : 0;
        __syncthreads();
        s[tid] += t;
        __syncthreads();
    }
    if (tid < SCAN_BLKS) bsum[tid] = s[tid] - v;   // exclusive
    if (tid == 0) rowptr[N_NODES] = E_EDGES;
}

__global__ __launch_bounds__(256) void scan3_both(
        int* __restrict__ rp_d, const int* __restrict__ bsum_d, int* __restrict__ cur_d,
        int* __restrict__ rp_s, const int* __restrict__ bsum_s, int* __restrict__ cur_s) {
    int set = blockIdx.x / SCAN_BLKS, blk = blockIdx.x % SCAN_BLKS;
    int* rowptr      = set ? rp_s   : rp_d;
    const int* bsum  = set ? bsum_s : bsum_d;
    int* cursor      = set ? cur_s  : cur_d;
    int idx = blk * 256 + threadIdx.x;
    if (idx < N_NODES) {
        int v = rowptr[idx] + bsum[blk];
        rowptr[idx] = v;
        cursor[idx] = v;
    }
}

// fused scatter: dst-CSR key (src,rel), src-CSR key (rel), and zidx map
__global__ __launch_bounds__(256) void scatter_both(
        const int* __restrict__ ei, const int* __restrict__ et,
        int* __restrict__ cur_d, int* __restrict__ cur_s,
        int* __restrict__ skey, int* __restrict__ skey_s,
        int* __restrict__ zidx) {
    int e = blockIdx.x * 256 + threadIdx.x;
    if (e >= E_EDGES) return;
    int s = ei[e], d = ei[E_EDGES + e], rt = et[e];
    int p = atomicAdd(&cur_d[d], 1);
    skey[p] = (s << 6) | rt;                 // dst-order: (src, rel)
    int qp = atomicAdd(&cur_s[s], 1);
    skey_s[qp] = rt;                         // src-order: rel only
    zidx[p] = qp;                            // dst-slot -> Z row (src-slot)
}

// ==== fused preprocessing: Bt1, Bt2, cvt_pad(x), hbA-zero, deg-zero ====
#define PREP_N1 (OUTW * KP1)                 // Bt1
#define PREP_N2 (OUTW * KP2)                 // Bt2
#define PREP_NC (MPAD * (KP1 / 8))           // cvt_pad x (ushort8 chunks)
#define PREP_NZ (MPAD * (KP2 / 8))           // hbA zero (ushort8 chunks)
#define PREP_TOT (PREP_N1 + PREP_N2 + PREP_NC + PREP_NZ + N_NODES)
__global__ __launch_bounds__(256) void prep_kernel(
        const float* __restrict__ basis1, ushort_t* __restrict__ Bt1,
        const float* __restrict__ basis2, ushort_t* __restrict__ Bt2,
        const float* __restrict__ x, ushort_t* __restrict__ xbA,
        ushort_t* __restrict__ hbA,
        int* __restrict__ dd, int* __restrict__ ds) {
    int idx = blockIdx.x * 256 + threadIdx.x;
    if (idx < PREP_N1) {
        int n = idx / KP1, k = idx - n * KP1;
        int b = n / HID, o = n - b * HID;
        float v = (k < IN_CH) ? basis1[((size_t)b * IN_CH + k) * HID + o] : 0.f;
        Bt1[idx] = f2bf_rne(v);
        return;
    }
    idx -= PREP_N1;
    if (idx < PREP_N2) {
        int n = idx / KP2, k = idx - n * KP2;
        int b = n / HID, o = n - b * HID;
        float v = (k < HID) ? basis2[((size_t)b * HID + k) * HID + o] : 0.f;
        Bt2[idx] = f2bf_rne(v);
        return;
    }
    idx -= PREP_N2;
    if (idx < PREP_NC) {                       // x -> bf16 padded
        constexpr int CH = KP1 / 8;
        int n = idx / CH, c = idx - n * CH;
        int k = c * 8;
        float v[8];
        if (n < N_NODES && k + 8 <= IN_CH) {
            float4 f0 = *(const float4*)&x[(size_t)n * IN_CH + k];
            float4 f1 = *(const float4*)&x[(size_t)n * IN_CH + k + 4];
            v[0]=f0.x; v[1]=f0.y; v[2]=f0.z; v[3]=f0.w;
            v[4]=f1.x; v[5]=f1.y; v[6]=f1.z; v[7]=f1.w;
        } else {
            #pragma unroll
            for (int i = 0; i < 8; i++)
                v[i] = (n < N_NODES && k + i < IN_CH) ? x[(size_t)n * IN_CH + k + i] : 0.f;
        }
        ushort8 hv;
        #pragma unroll
        for (int i = 0; i < 8; i++) hv[i] = f2bf_rne(v[i]);
        *(ushort8*)&xbA[(size_t)n * KP1 + k] = hv;
        return;
    }
    idx -= PREP_NC;
    if (idx < PREP_NZ) {                       // hbA zero (pads must be 0)
        ushort8 z = {};
        *(ushort8*)&hbA[(size_t)idx * 8] = z;
        return;
    }
    idx -= PREP_NZ;
    if (idx < N_NODES) { dd[idx] = 0; ds[idx] = 0; }
}

// ---- MFMA GEMM + fused q/k partial dots (plane-major partials) ----
// xbh[M,800](bf16) = Ab[M,KP](bf16) * B[KP,800]
// 480 blocks = 10 col-blocks x 48 row-groups, XCD-affine (FETCH ~= A once).
// qk partials now go to DENSE per-(cb,slot) planes xqp/xkp[plane][MPAD]:
// each wave writes 32 contiguous floats per plane -> full-line coverage.
// r6's row-major layout had all 10 cbs partial-writing every row's 64-B
// line -> ~26 MB RMW fetch + ~30 MB write per dispatch (measured).
// __launch_bounds__(512, 2): MUST stay 2 (r5: (512,4) capped VGPR at 64 ->
// scratch spills, FETCH 16->150 MB).
template<int KP>
__global__ __launch_bounds__(512, 2) void gemm_mfma(
        const ushort_t* __restrict__ Ab, const ushort_t* __restrict__ Bt,
        ushort_t* __restrict__ xbh, int M,
        const float* __restrict__ qw, const float* __restrict__ kw,
        float* __restrict__ xqp, float* __restrict__ xkp) {
    constexpr int KSTEPS = KP / 32;           // 10 (layer1) / 4 (layer2)
    constexpr int SW = KP + 8;                // LDS col stride (ushorts)
    constexpr int CH = KP / 8;
    __shared__ ushort_t Bs[80 * SW];          // 52.5 KB (L1) / 21.3 KB (L2)
    __shared__ float sqk[2 * HID];            // q then k (800 B)
    int tid = threadIdx.x, lane = tid & 63, wave = tid >> 6;
    int ml = lane & 15, quad = lane >> 4;
    // XCD-affine de-swizzle: b = (rg&7) + 8*cb + 80*(rg>>3)
    int b = blockIdx.x;
    int xcd = b & 7, qq = b >> 3;
    int cb = qq % 10;                         // 10 col blocks of 80
    int rg = xcd + 8 * (qq / 10);             // 0..47
    int col0 = cb * 80;

    // ---- stage B tile once (coalesced 16B chunks) + q/k vectors ----
    if (tid < 2 * HID) sqk[tid] = (tid < HID) ? qw[tid] : kw[tid - HID];
    for (int t = tid; t < 80 * CH; t += 512) {
        int c = t / CH, ch = t - c * CH;
        *(ushort8*)&Bs[c * SW + ch * 8] =
            *(const ushort8*)&Bt[(size_t)(col0 + c) * KP + ch * 8];
    }
    __syncthreads();                          // the ONLY barrier

    const ushort_t* bb = &Bs[(size_t)ml * SW + quad * 8];

    // per-lane qk-partial constants for this col-block
    int bLo = col0 / 100, bHi = (col0 + 79) / 100;
    int split = (bHi != bLo) ? bHi * 100 : (col0 + 160);   // unreachable if 1 slice
    float* qpl = xqp + (size_t)(cb * 2) * MPAD;      // Lo plane
    float* kpl = xkp + (size_t)(cb * 2) * MPAD;
    float* qph = qpl + MPAD;                          // Hi plane
    float* kph = kpl + MPAD;
    float qv[5], kv[5];
    int himask = 0;
    #pragma unroll
    for (int nt = 0; nt < 5; nt++) {
        int c = col0 + nt * 16 + ml;
        int cm = c % 100;
        qv[nt] = sqk[cm]; kv[nt] = sqk[100 + cm];
        if (c >= split) himask |= 1 << nt;
    }

    for (int g = rg; g < NPAIR; g += GEMM_RG) {
        int rbase = g * 256 + wave * 32;      // this wave's 32 rows
        const ushort_t* ar0 = Ab + (size_t)(rbase + ml) * KP + quad * 8;
        const ushort_t* ar1 = ar0 + (size_t)16 * KP;
        short8 a0[KSTEPS], a1[KSTEPS];
        #pragma unroll
        for (int ks = 0; ks < KSTEPS; ks++) {
            a0[ks] = *(const short8*)(ar0 + ks * 32);
            a1[ks] = *(const short8*)(ar1 + ks * 32);
        }
        f32x4 acc0[5] = {}, acc1[5] = {};
        #pragma unroll
        for (int ks = 0; ks < KSTEPS; ks++) {
            short8 bf[5];
            #pragma unroll
            for (int nt = 0; nt < 5; nt++)
                bf[nt] = *(const short8*)(bb + nt * 16 * SW + ks * 32);
            #pragma unroll
            for (int nt = 0; nt < 5; nt++) {
                acc0[nt] = __builtin_amdgcn_mfma_f32_16x16x32_bf16(
                               a0[ks], bf[nt], acc0[nt], 0, 0, 0);
                acc1[nt] = __builtin_amdgcn_mfma_f32_16x16x32_bf16(
                               a1[ks], bf[nt], acc1[nt], 0, 0, 0);
            }
        }
        // epilogue (C layout: row = quad*4 + r, col = nt*16 + ml)
        #pragma unroll
        for (int nt = 0; nt < 5; nt++) {
            #pragma unroll
            for (int r = 0; r < 4; r++) {
                int g0 = rbase + quad * 4 + r;
                if (g0 < M)
                    xbh[(size_t)g0 * OUTW + col0 + nt * 16 + ml] =
                        f2bf_rne(acc0[nt][r]);
                int g1 = g0 + 16;
                if (g1 < M)
                    xbh[(size_t)g1 * OUTW + col0 + nt * 16 + ml] =
                        f2bf_rne(acc1[nt][r]);
            }
        }
        // fused q/k partial dots -> dense planes (contiguous per wave)
        #pragma unroll
        for (int r = 0; r < 4; r++) {
            float pqL = 0, pqH = 0, pkL = 0, pkH = 0;   // acc0 rows
            float sqL = 0, sqH = 0, skL = 0, skH = 0;   // acc1 rows
            #pragma unroll
            for (int nt = 0; nt < 5; nt++) {
                float v0 = acc0[nt][r], v1 = acc1[nt][r];
                if (himask & (1 << nt)) {
                    pqH = fmaf(v0, qv[nt], pqH); pkH = fmaf(v0, kv[nt], pkH);
                    sqH = fmaf(v1, qv[nt], sqH); skH = fmaf(v1, kv[nt], skH);
                } else {
                    pqL = fmaf(v0, qv[nt], pqL); pkL = fmaf(v0, kv[nt], pkL);
                    sqL = fmaf(v1, qv[nt], sqL); skL = fmaf(v1, kv[nt], skL);
                }
            }
            #pragma unroll
            for (int off = 1; off < 16; off <<= 1) {
                pqL += __shfl_xor(pqL, off); pqH += __shfl_xor(pqH, off);
                pkL += __shfl_xor(pkL, off); pkH += __shfl_xor(pkH, off);
                sqL += __shfl_xor(sqL, off); sqH += __shfl_xor(sqH, off);
                skL += __shfl_xor(skL, off); skH += __shfl_xor(skH, off);
            }
            if (ml == 0) {
                int r0i = rbase + quad * 4 + r, r1i = r0i + 16;
                qpl[r0i] = pqL; kpl[r0i] = pkL;
                qpl[r1i] = sqL; kpl[r1i] = skL;
                if (bHi != bLo) {
                    qph[r0i] = pqH; kph[r0i] = pkH;
                    qph[r1i] = sqH; kph[r1i] = skH;
                }
            }
        }
    }
}

// ==== src-major, batched-4 Z rows; comp in LDS; keys via register window ====
// PROLOGUE: reduce qk planes -> dense xbq/xbk (every node visited, incl.
// isolated ones -- before the beg==end early-out).
__global__ __launch_bounds__(256) void compute_z(
        const int* __restrict__ rowptr_s, const int* __restrict__ skey_s,
        const float* __restrict__ comp, const ushort_t* __restrict__ xbh,
        ushort_t* __restrict__ Z,
        const float* __restrict__ xqp, const float* __restrict__ xkp,
        float* __restrict__ xbq, float* __restrict__ xbk) {
    __shared__ float scomp[R_REL * NB];   // 1.6 KB
    int tid = threadIdx.x;
    for (int i = tid; i < R_REL * NB; i += 256) scomp[i] = comp[i];
    __syncthreads();
    int wave = tid >> 6, lane = tid & 63;
    int s = blockIdx.x * 4 + wave;
    if (s >= N_NODES) return;

    // ---- qk plane reduce: lanes 0-7 q, 8-15 k ----
    if (lane < 16) {
        int b = lane & 7;
        const float* src = (lane < 8) ? xqp : xkp;
        float v = src[(size_t)PAIR_A[b] * MPAD + s]
                + src[(size_t)PAIR_B[b] * MPAD + s];
        float* dst = (lane < 8) ? xbq : xbk;
        dst[(size_t)s * NB + b] = v;
    }

    int beg = rowptr_s[s], end = rowptr_s[s + 1];
    if (beg == end) return;
    int eg = lane >> 4, c16 = lane & 15;
    int cbase = c16 * 8;
    float xr[NB][8];
    #pragma unroll
    for (int b = 0; b < NB; b++)
        #pragma unroll
        for (int i = 0; i < 8; i++) xr[b][i] = 0.f;
    if (cbase < HID) {
        #pragma unroll
        for (int b = 0; b < NB; b++) {
            const ushort_t* base = xbh + (size_t)s * OUTW + b * HID + cbase;
            ushort4 v0 = *(const ushort4*)base;       // 8B aligned
            xr[b][0] = bf2f(v0.x); xr[b][1] = bf2f(v0.y);
            xr[b][2] = bf2f(v0.z); xr[b][3] = bf2f(v0.w);
            if (cbase + 8 <= HID) {
                ushort4 v1 = *(const ushort4*)(base + 4);
                xr[b][4] = bf2f(v1.x); xr[b][5] = bf2f(v1.y);
                xr[b][6] = bf2f(v1.z); xr[b][7] = bf2f(v1.w);
            }
        }
    }
    for (int w0 = beg; w0 < end; w0 += 64) {
        // one coalesced key load covers the next 64 edges (16 quads)
        int kw = (w0 + lane < end) ? skey_s[w0 + lane] : 0;
        int wend = w0 + 64 < end ? w0 + 64 : end;
        for (int p0 = w0; p0 < wend; p0 += 4) {
            int j = p0 - w0 + eg;              // < 64 always
            int rt = __shfl(kw, j) & 63;       // zero memory ops in chain
            int p = p0 + eg;
            const float* cr = &scomp[rt * NB];
            float z[8] = {};
            #pragma unroll
            for (int b = 0; b < NB; b++) {
                float cb = cr[b];
                #pragma unroll
                for (int i = 0; i < 8; i++) z[i] = fmaf(cb, xr[b][i], z[i]);
            }
            ushort8 zz;
            #pragma unroll
            for (int i = 0; i < 8; i++) zz[i] = f2bf_rne(z[i]);
            // guard: cbase 104/112/120 would overrun the 104-ushort row
            if (p < end && cbase < ZW)
                *(ushort8*)&Z[(size_t)p * ZW + cbase] = zz;   // 16B, coalesced
        }
    }
}

// ==== dst-major: online softmax + paired-edge Z gather + bias; comp in LDS ====
// q/k read dense from xbq/xbk (reduced by compute_z's prologue).
// WB=1: write relu'd bf16 into padded layer-2 A buffer (hb) instead of f32 h.
template<int WB>
__global__ __launch_bounds__(256) void msg_soft(
        const int* __restrict__ rowptr, const int* __restrict__ skey,
        const int* __restrict__ zidx,
        const float* __restrict__ comp, const ushort_t* __restrict__ Z,
        const float* __restrict__ xbq, const float* __restrict__ xbk,
        const float* __restrict__ bias, float* __restrict__ h,
        ushort_t* __restrict__ hb) {
    __shared__ float scomp[R_REL * NB];   // 1.6 KB
    int tid = threadIdx.x;
    for (int i = tid; i < R_REL * NB; i += 256) scomp[i] = comp[i];
    __syncthreads();
    int wave = tid >> 6, lane = tid & 63;
    int d = blockIdx.x * 4 + wave;
    if (d >= N_NODES) return;
    int beg = rowptr[d], end = rowptr[d + 1];

    float4 qd0 = *(const float4*)&xbq[d * NB];
    float4 qd1 = *(const float4*)&xbq[d * NB + 4];

    int l5 = lane & 31;
    bool act = l5 < 25;
    int oc = l5 * 4;                  // channel base (4 channels per lane)
    f32x4 acc = {0.f, 0.f, 0.f, 0.f};
    float m = -1e30f, l = 0.f;

    for (int c0 = beg; c0 < end; c0 += 64) {
        int p = c0 + lane;
        bool valid = p < end;
        float a = -1e30f;
        int zi = 0;
        if (valid) {
            int key = skey[p];
            zi = zidx[p];
            int s = key >> 6, rt = key & 63;
            const float4 c0v = *(const float4*)&scomp[rt * NB];
            const float4 c1v = *(const float4*)&scomp[rt * NB + 4];
            const float4 k0v = *(const float4*)&xbk[s * NB];
            const float4 k1v = *(const float4*)&xbk[s * NB + 4];
            float qi = c0v.x*qd0.x + c0v.y*qd0.y + c0v.z*qd0.z + c0v.w*qd0.w
                     + c1v.x*qd1.x + c1v.y*qd1.y + c1v.z*qd1.z + c1v.w*qd1.w;
            float kj = c0v.x*k0v.x + c0v.y*k0v.y + c0v.z*k0v.z + c0v.w*k0v.w
                     + c1v.x*k1v.x + c1v.y*k1v.y + c1v.z*k1v.z + c1v.w*k1v.w;
            float av = qi + kj;
            a = av > 0.f ? av : 0.2f * av;  // leaky_relu 0.2
        }
        float cm = a;
        #pragma unroll
        for (int off = 32; off; off >>= 1) cm = fmaxf(cm, __shfl_xor(cm, off));
        float M = fmaxf(m, cm);
        float scale = __expf(m - M);
        acc *= scale; l *= scale; m = M;
        float wgt = valid ? __expf(a - M) : 0.f;
        float cs = wgt;
        #pragma unroll
        for (int off = 32; off; off >>= 1) cs += __shfl_xor(cs, off);
        l += cs;
        int cnt = end - c0; if (cnt > 64) cnt = 64;
        for (int j = 0; j < cnt; j += 2) {
            int jj = j + (lane >> 5);         // even half: j, odd half: j+1
            float wj = __shfl(wgt, jj);       // invalid -> 0
            int   zj = __shfl(zi, jj);
            if (act) {
                ushort4 zz = *(const ushort4*)&Z[(size_t)zj * ZW + oc];
                acc.x = fmaf(wj, bf2f(zz.x), acc.x);
                acc.y = fmaf(wj, bf2f(zz.y), acc.y);
                acc.z = fmaf(wj, bf2f(zz.z), acc.z);
                acc.w = fmaf(wj, bf2f(zz.w), acc.w);
            }
        }
    }
    // combine even/odd-edge halves: lane ℓ (<25) += lane ℓ+32
    #pragma unroll
    for (int i = 0; i < 4; i++) acc[i] += __shfl_xor(acc[i], 32);
    if (lane < 25) {
        float inv = 1.f / (l + 1e-16f);
        float4 r;
        r.x = bias[oc]     + acc.x * inv;
        r.y = bias[oc + 1] + acc.y * inv;
        r.z = bias[oc + 2] + acc.z * inv;
        r.w = bias[oc + 3] + acc.w * inv;
        if (WB) {
            ushort4 o;
            o.x = f2bf_rne(fmaxf(r.x, 0.f));
            o.y = f2bf_rne(fmaxf(r.y, 0.f));
            o.z = f2bf_rne(fmaxf(r.z, 0.f));
            o.w = f2bf_rne(fmaxf(r.w, 0.f));
            *(ushort4*)&hb[(size_t)d * KP2 + oc] = o;   // 8B aligned
        } else {
            *(float4*)&h[(size_t)d * HID + oc] = r;     // 16B aligned
        }
    }
}

// ---- pooled = mean(relu(h2[qidx])); out = pooled @ Wl^T + bl ----
__global__ __launch_bounds__(128) void head_kernel(
        const float* __restrict__ h2, const int* __restrict__ qidx,
        const float* __restrict__ Wl, const float* __restrict__ bl,
        float* __restrict__ out) {
    __shared__ float pooled[HID];
    int tid = threadIdx.x;
    if (tid < HID) {
        float s = 0.f;
        for (int i = 0; i < NQ; i++)
            s += fmaxf(h2[(size_t)qidx[i] * HID + tid], 0.f);
        pooled[tid] = s * (1.0f / NQ);
    }
    __syncthreads();
    if (tid < CLS) {
        float s = bl[tid];
        for (int o = 0; o < HID; o++) s = fmaf(pooled[o], Wl[tid * HID + o], s);
        out[tid] = s;
    }
}

extern "C" void kernel_launch(void* const* d_in, const int* in_sizes, int n_in,
                              void* d_out, int out_size, void* d_ws, size_t ws_size,
                              hipStream_t stream) {
    const float* x      = (const float*)d_in[0];
    const int*   ei     = (const int*)  d_in[1];
    const int*   et     = (const int*)  d_in[2];
    const int*   qidx   = (const int*)  d_in[3];
    const float* comp1  = (const float*)d_in[4];
    const float* basis1 = (const float*)d_in[5];
    const float* q1     = (const float*)d_in[6];
    const float* k1     = (const float*)d_in[7];
    const float* b1     = (const float*)d_in[8];
    const float* comp2  = (const float*)d_in[9];
    const float* basis2 = (const float*)d_in[10];
    const float* q2     = (const float*)d_in[11];
    const float* k2     = (const float*)d_in[12];
    const float* b2     = (const float*)d_in[13];
    const float* Wl     = (const float*)d_in[14];
    const float* bl     = (const float*)d_in[15];
    float* out = (float*)d_out;

    char* w = (char*)d_ws;
    size_t off = 0;
    auto alloc = [&](size_t nbytes) {
        void* p = (void*)(w + off);
        off += ((nbytes + 255) / 256) * 256;
        return p;
    };
    ushort_t* xbh    = (ushort_t*)alloc((size_t)N_NODES * OUTW * 2); // 32 MB
    ushort_t* Z      = (ushort_t*)alloc((size_t)E_EDGES * ZW * 2);   // 66.6 MB
    float*    h2     = (float*)alloc((size_t)N_NODES * HID * 4);     // 8 MB
    ushort_t* Bt1    = (ushort_t*)alloc((size_t)OUTW * KP1 * 2);     // 512 KB
    ushort_t* Bt2    = (ushort_t*)alloc((size_t)OUTW * KP2 * 2);     // 205 KB
    ushort_t* xbA    = (ushort_t*)alloc((size_t)MPAD * KP1 * 2);     // 12.9 MB
    ushort_t* hbA    = (ushort_t*)alloc((size_t)MPAD * KP2 * 2);     // 5.2 MB
    float*    xqp    = (float*)alloc((size_t)NPLANE * MPAD * 4);     // 1.6 MB
    float*    xkp    = (float*)alloc((size_t)NPLANE * MPAD * 4);     // 1.6 MB
    float*    xbq    = (float*)alloc((size_t)N_NODES * NB * 4);      // 640 KB
    float*    xbk    = (float*)alloc((size_t)N_NODES * NB * 4);      // 640 KB
    int*      deg_d  = (int*)alloc(N_NODES * 4);
    int*      deg_s  = (int*)alloc(N_NODES * 4);
    int*      rp_d   = (int*)alloc((N_NODES + 1) * 4);
    int*      rp_s   = (int*)alloc((N_NODES + 1) * 4);
    int*      cur_d  = (int*)alloc(N_NODES * 4);
    int*      cur_s  = (int*)alloc(N_NODES * 4);
    int*      bsum_d = (int*)alloc(SCAN_BLKS * 4);
    int*      bsum_s = (int*)alloc(SCAN_BLKS * 4);
    int*      skey   = (int*)alloc(E_EDGES * 4);
    int*      skey_s = (int*)alloc(E_EDGES * 4);
    int*      zidx   = (int*)alloc(E_EDGES * 4);

    // ---- fused preprocessing + CSR build ----
    prep_kernel<<<(PREP_TOT + 255) / 256, 256, 0, stream>>>(
        basis1, Bt1, basis2, Bt2, x, xbA, hbA, deg_d, deg_s);
    hist2_kernel<<<(E_EDGES + 255) / 256, 256, 0, stream>>>(ei, deg_d, deg_s);
    scan1_both<<<2 * SCAN_BLKS, 256, 0, stream>>>(deg_d, rp_d, bsum_d, deg_s, rp_s, bsum_s);
    scan2_both<<<2, 128, 0, stream>>>(bsum_d, rp_d, bsum_s, rp_s);
    scan3_both<<<2 * SCAN_BLKS, 256, 0, stream>>>(rp_d, bsum_d, cur_d, rp_s, bsum_s, cur_s);
    scatter_both<<<(E_EDGES + 255) / 256, 256, 0, stream>>>(ei, et, cur_d, cur_s, skey, skey_s, zidx);

    // ---- layer 1 (msg_soft writes relu'd bf16 straight into hbA) ----
    gemm_mfma<KP1><<<10 * GEMM_RG, 512, 0, stream>>>(xbA, Bt1, xbh, N_NODES, q1, k1, xqp, xkp);
    compute_z<<<(N_NODES + 3) / 4, 256, 0, stream>>>(rp_s, skey_s, comp1, xbh, Z, xqp, xkp, xbq, xbk);
    msg_soft<1><<<(N_NODES + 3) / 4, 256, 0, stream>>>(rp_d, skey, zidx, comp1, Z, xbq, xbk, b1, (float*)nullptr, hbA);

    // ---- layer 2 ----
    gemm_mfma<KP2><<<10 * GEMM_RG, 512, 0, stream>>>(hbA, Bt2, xbh, N_NODES, q2, k2, xqp, xkp);
    compute_z<<<(N_NODES + 3) / 4, 256, 0, stream>>>(rp_s, skey_s, comp2, xbh, Z, xqp, xkp, xbq, xbk);
    msg_soft<0><<<(N_NODES + 3) / 4, 256, 0, stream>>>(rp_d, skey, zidx, comp2, Z, xbq, xbk, b2, h2, (ushort_t*)nullptr);

    head_kernel<<<1, 128, 0, stream>>>(h2, qidx, Wl, bl, out);
}

// Round 9
// 380.923 us; speedup vs baseline: 1.2682x; 1.0170x over previous
//
#include <hip/hip_runtime.h>
#include <math.h>

#define N_NODES 20000
#define E_EDGES 320000
#define IN_CH   300
#define HID     100
#define R_REL   50
#define NB      8
#define CLS     3
#define NQ      64
#define OUTW    800   // NB * HID
#define ZW      104   // Z row stride (ushorts): 208-B rows (16B-aligned), exact fit
#define KP1     320
#define KP2     128
#define MPAD    20224 // 79 * 256 (row-chunk padded M for A bf16 buffers)
#define NPAIR   79    // MPAD / 256
#define GEMM_RG 48    // row-groups; grid = 10 col-blocks * 48 = 480 blocks
#define SCAN_BLKS ((N_NODES + 255) / 256)   // 79

typedef unsigned short ushort_t;
typedef __attribute__((ext_vector_type(8))) short     short8;
typedef __attribute__((ext_vector_type(8))) unsigned short ushort8;
typedef __attribute__((ext_vector_type(4))) float     f32x4;
typedef __attribute__((ext_vector_type(2))) float     f32x2;

__device__ __forceinline__ ushort_t f2bf_rne(float f) {   // round-nearest-even
    unsigned u = __float_as_uint(f);
    unsigned r = (u + 0x7fffu + ((u >> 16) & 1u)) >> 16;
    return (ushort_t)r;
}
__device__ __forceinline__ float bf2f(ushort_t u) {
    return __uint_as_float((unsigned)u << 16);
}

// ============================ CSR build =================================
__global__ __launch_bounds__(256) void hist2_kernel(
        const int* __restrict__ ei, int* __restrict__ dd,
        int* __restrict__ ds) {
    int e = blockIdx.x * 256 + threadIdx.x;
    if (e < E_EDGES) {
        atomicAdd(&dd[ei[E_EDGES + e]], 1);
        atomicAdd(&ds[ei[e]], 1);
    }
}

// dual-set scans: blockIdx selects (deg_d...) or (deg_s...) set
__global__ __launch_bounds__(256) void scan1_both(
        const int* __restrict__ deg_d, int* __restrict__ rp_d, int* __restrict__ bsum_d,
        const int* __restrict__ deg_s, int* __restrict__ rp_s, int* __restrict__ bsum_s) {
    int set = blockIdx.x / SCAN_BLKS, blk = blockIdx.x % SCAN_BLKS;
    const int* deg = set ? deg_s : deg_d;
    int* rowptr    = set ? rp_s  : rp_d;
    int* bsum      = set ? bsum_s : bsum_d;
    __shared__ int s[256];
    int tid = threadIdx.x;
    int idx = blk * 256 + tid;
    int v = (idx < N_NODES) ? deg[idx] : 0;
    s[tid] = v; __syncthreads();
    #pragma unroll
    for (int off = 1; off < 256; off <<= 1) {
        int t = (tid >= off) ? s[tid - off] : 0;
        __syncthreads();
        s[tid] += t;
        __syncthreads();
    }
    if (idx < N_NODES) rowptr[idx] = s[tid] - v;   // exclusive
    if (tid == 255) bsum[blk] = s[255];
}

__global__ __launch_bounds__(128) void scan2_both(
        int* __restrict__ bsum_d, int* __restrict__ rp_d,
        int* __restrict__ bsum_s, int* __restrict__ rp_s) {
    int* bsum   = blockIdx.x ? bsum_s : bsum_d;
    int* rowptr = blockIdx.x ? rp_s   : rp_d;
    __shared__ int s[128];
    int tid = threadIdx.x;
    int v = (tid < SCAN_BLKS) ? bsum[tid] : 0;
    s[tid] = v; __syncthreads();
    #pragma unroll
    for (int off = 1; off < 128; off <<= 1) {
        int t = (tid >= off) ? s[tid - off] : 0;
        __syncthreads();
        s[tid] += t;
        __syncthreads();
    }
    if (tid < SCAN_BLKS) bsum[tid] = s[tid] - v;   // exclusive
    if (tid == 0) rowptr[N_NODES] = E_EDGES;
}

__global__ __launch_bounds__(256) void scan3_both(
        int* __restrict__ rp_d, const int* __restrict__ bsum_d, int* __restrict__ cur_d,
        int* __restrict__ rp_s, const int* __restrict__ bsum_s, int* __restrict__ cur_s) {
    int set = blockIdx.x / SCAN_BLKS, blk = blockIdx.x % SCAN_BLKS;
    int* rowptr      = set ? rp_s   : rp_d;
    const int* bsum  = set ? bsum_s : bsum_d;
    int* cursor      = set ? cur_s  : cur_d;
    int idx = blk * 256 + threadIdx.x;
    if (idx < N_NODES) {
        int v = rowptr[idx] + bsum[blk];
        rowptr[idx] = v;
        cursor[idx] = v;
    }
}

// fused scatter: dst-CSR key (src,rel), src-CSR key (rel), and zidx map
__global__ __launch_bounds__(256) void scatter_both(
        const int* __restrict__ ei, const int* __restrict__ et,
        int* __restrict__ cur_d, int* __restrict__ cur_s,
        int* __restrict__ skey, int* __restrict__ skey_s,
        int* __restrict__ zidx) {
    int e = blockIdx.x * 256 + threadIdx.x;
    if (e >= E_EDGES) return;
    int s = ei[e], d = ei[E_EDGES + e], rt = et[e];
    int p = atomicAdd(&cur_d[d], 1);
    skey[p] = (s << 6) | rt;                 // dst-order: (src, rel)
    int qp = atomicAdd(&cur_s[s], 1);
    skey_s[qp] = rt;                         // src-order: rel only
    zidx[p] = qp;                            // dst-slot -> Z row (src-slot)
}

// ==== fused preprocessing: Bt1, Bt2, cvt_pad(x), hbA-zero, deg-zero ====
#define PREP_N1 (OUTW * KP1)                 // Bt1
#define PREP_N2 (OUTW * KP2)                 // Bt2
#define PREP_NC (MPAD * (KP1 / 8))           // cvt_pad x (ushort8 chunks)
#define PREP_NZ (MPAD * (KP2 / 8))           // hbA zero (ushort8 chunks)
#define PREP_TOT (PREP_N1 + PREP_N2 + PREP_NC + PREP_NZ + N_NODES)
__global__ __launch_bounds__(256) void prep_kernel(
        const float* __restrict__ basis1, ushort_t* __restrict__ Bt1,
        const float* __restrict__ basis2, ushort_t* __restrict__ Bt2,
        const float* __restrict__ x, ushort_t* __restrict__ xbA,
        ushort_t* __restrict__ hbA,
        int* __restrict__ dd, int* __restrict__ ds) {
    int idx = blockIdx.x * 256 + threadIdx.x;
    if (idx < PREP_N1) {
        int n = idx / KP1, k = idx - n * KP1;
        int b = n / HID, o = n - b * HID;
        float v = (k < IN_CH) ? basis1[((size_t)b * IN_CH + k) * HID + o] : 0.f;
        Bt1[idx] = f2bf_rne(v);
        return;
    }
    idx -= PREP_N1;
    if (idx < PREP_N2) {
        int n = idx / KP2, k = idx - n * KP2;
        int b = n / HID, o = n - b * HID;
        float v = (k < HID) ? basis2[((size_t)b * HID + k) * HID + o] : 0.f;
        Bt2[idx] = f2bf_rne(v);
        return;
    }
    idx -= PREP_N2;
    if (idx < PREP_NC) {                       // x -> bf16 padded
        constexpr int CH = KP1 / 8;
        int n = idx / CH, c = idx - n * CH;
        int k = c * 8;
        float v[8];
        if (n < N_NODES && k + 8 <= IN_CH) {
            float4 f0 = *(const float4*)&x[(size_t)n * IN_CH + k];
            float4 f1 = *(const float4*)&x[(size_t)n * IN_CH + k + 4];
            v[0]=f0.x; v[1]=f0.y; v[2]=f0.z; v[3]=f0.w;
            v[4]=f1.x; v[5]=f1.y; v[6]=f1.z; v[7]=f1.w;
        } else {
            #pragma unroll
            for (int i = 0; i < 8; i++)
                v[i] = (n < N_NODES && k + i < IN_CH) ? x[(size_t)n * IN_CH + k + i] : 0.f;
        }
        ushort8 hv;
        #pragma unroll
        for (int i = 0; i < 8; i++) hv[i] = f2bf_rne(v[i]);
        *(ushort8*)&xbA[(size_t)n * KP1 + k] = hv;
        return;
    }
    idx -= PREP_NC;
    if (idx < PREP_NZ) {                       // hbA zero (pads must be 0)
        ushort8 z = {};
        *(ushort8*)&hbA[(size_t)idx * 8] = z;
        return;
    }
    idx -= PREP_NZ;
    if (idx < N_NODES) { dd[idx] = 0; ds[idx] = 0; }
}

// ---- MFMA GEMM: xbh[M,800](bf16) = Ab[M,KP](bf16) * B[KP,800] ----
// r3's proven form (47 us, FETCH ~16 MB). qk fusion REVERTED: both the
// row-major (r6: +26 MB RMW) and plane-major (r7: 73 us) epilogues cost
// more inside this latency-bound kernel than the ~20 us they saved; qk
// now rides compute_z's existing xbh row loads instead.
// 480 blocks = 10 col-blocks (80 cols) x 48 row-groups, 512 threads.
// XCD-affine: all 10 col-blocks of a row-group land on ONE XCD -> A fetched
// from HBM once, 9/10 reads hit that XCD's private L2 (verified r3).
// __launch_bounds__(512, 2): MUST stay 2 (r5: (512,4) capped VGPR at 64 ->
// scratch spills, FETCH 16->150 MB).
template<int KP>
__global__ __launch_bounds__(512, 2) void gemm_mfma(
        const ushort_t* __restrict__ Ab, const ushort_t* __restrict__ Bt,
        ushort_t* __restrict__ xbh, int M) {
    constexpr int KSTEPS = KP / 32;           // 10 (layer1) / 4 (layer2)
    constexpr int SW = KP + 8;                // LDS col stride (ushorts)
    constexpr int CH = KP / 8;
    __shared__ ushort_t Bs[80 * SW];          // 52.5 KB (L1) / 21.3 KB (L2)
    int tid = threadIdx.x, lane = tid & 63, wave = tid >> 6;
    int ml = lane & 15, quad = lane >> 4;
    // XCD-affine de-swizzle: b = (rg&7) + 8*cb + 80*(rg>>3)
    int b = blockIdx.x;
    int xcd = b & 7, qq = b >> 3;
    int cb = qq % 10;                         // 10 col blocks of 80
    int rg = xcd + 8 * (qq / 10);             // 0..47
    int col0 = cb * 80;

    // ---- stage B tile once (coalesced 16B chunks) ----
    for (int t = tid; t < 80 * CH; t += 512) {
        int c = t / CH, ch = t - c * CH;
        *(ushort8*)&Bs[c * SW + ch * 8] =
            *(const ushort8*)&Bt[(size_t)(col0 + c) * KP + ch * 8];
    }
    __syncthreads();                          // the ONLY barrier

    const ushort_t* bb = &Bs[(size_t)ml * SW + quad * 8];

    for (int g = rg; g < NPAIR; g += GEMM_RG) {
        int rbase = g * 256 + wave * 32;      // this wave's 32 rows
        const ushort_t* ar0 = Ab + (size_t)(rbase + ml) * KP + quad * 8;
        const ushort_t* ar1 = ar0 + (size_t)16 * KP;
        short8 a0[KSTEPS], a1[KSTEPS];
        #pragma unroll
        for (int ks = 0; ks < KSTEPS; ks++) {
            a0[ks] = *(const short8*)(ar0 + ks * 32);
            a1[ks] = *(const short8*)(ar1 + ks * 32);
        }
        f32x4 acc0[5] = {}, acc1[5] = {};
        #pragma unroll
        for (int ks = 0; ks < KSTEPS; ks++) {
            short8 bf[5];
            #pragma unroll
            for (int nt = 0; nt < 5; nt++)
                bf[nt] = *(const short8*)(bb + nt * 16 * SW + ks * 32);
            #pragma unroll
            for (int nt = 0; nt < 5; nt++) {
                acc0[nt] = __builtin_amdgcn_mfma_f32_16x16x32_bf16(
                               a0[ks], bf[nt], acc0[nt], 0, 0, 0);
                acc1[nt] = __builtin_amdgcn_mfma_f32_16x16x32_bf16(
                               a1[ks], bf[nt], acc1[nt], 0, 0, 0);
            }
        }
        // epilogue (C layout: row = quad*4 + r, col = nt*16 + ml)
        #pragma unroll
        for (int nt = 0; nt < 5; nt++) {
            #pragma unroll
            for (int r = 0; r < 4; r++) {
                int g0 = rbase + quad * 4 + r;
                if (g0 < M)
                    xbh[(size_t)g0 * OUTW + col0 + nt * 16 + ml] =
                        f2bf_rne(acc0[nt][r]);
                int g1 = g0 + 16;
                if (g1 < M)
                    xbh[(size_t)g1 * OUTW + col0 + nt * 16 + ml] =
                        f2bf_rne(acc1[nt][r]);
            }
        }
    }
}

// ==== src-major, batched-4 Z rows; comp in LDS; keys via register window ====
// PROLOGUE: compute xbq/xbk from the SAME xr registers this kernel already
// loads -- removes the qk3 kernel and its 32 MB xbh re-read. Runs before
// the beg==end early-out so every node (incl. edge-less dsts) gets q/k.
// Cost: ~128 fmaf + 15 shfl-steps per node-wave (~4 us machine-wide).
__global__ __launch_bounds__(256) void compute_z(
        const int* __restrict__ rowptr_s, const int* __restrict__ skey_s,
        const float* __restrict__ comp, const ushort_t* __restrict__ xbh,
        ushort_t* __restrict__ Z,
        const float* __restrict__ qw, const float* __restrict__ kw,
        float* __restrict__ xbq, float* __restrict__ xbk) {
    __shared__ float scomp[R_REL * NB];   // 1.6 KB
    __shared__ float sqk[208];            // q[0..99],pad4, k[0..99],pad4
    int tid = threadIdx.x;
    for (int i = tid; i < R_REL * NB; i += 256) scomp[i] = comp[i];
    if (tid < 208) {
        float v = 0.f;
        if (tid < HID) v = qw[tid];
        else if (tid >= 104 && tid < 104 + HID) v = kw[tid - 104];
        sqk[tid] = v;
    }
    __syncthreads();
    int wave = tid >> 6, lane = tid & 63;
    int s = blockIdx.x * 4 + wave;
    if (s >= N_NODES) return;

    int eg = lane >> 4, c16 = lane & 15;
    int cbase = c16 * 8;
    float xr[NB][8];
    #pragma unroll
    for (int b = 0; b < NB; b++)
        #pragma unroll
        for (int i = 0; i < 8; i++) xr[b][i] = 0.f;
    if (cbase < HID) {
        #pragma unroll
        for (int b = 0; b < NB; b++) {
            const ushort_t* base = xbh + (size_t)s * OUTW + b * HID + cbase;
            ushort4 v0 = *(const ushort4*)base;       // 8B aligned
            xr[b][0] = bf2f(v0.x); xr[b][1] = bf2f(v0.y);
            xr[b][2] = bf2f(v0.z); xr[b][3] = bf2f(v0.w);
            if (cbase + 8 <= HID) {
                ushort4 v1 = *(const ushort4*)(base + 4);
                xr[b][4] = bf2f(v1.x); xr[b][5] = bf2f(v1.y);
                xr[b][6] = bf2f(v1.z); xr[b][7] = bf2f(v1.w);
            }
        }
    }

    // ---- fused qk: per-lane partial dots over this lane's 8 channels ----
    {
        float aq[NB], ak[NB];
        #pragma unroll
        for (int b = 0; b < NB; b++) { aq[b] = 0.f; ak[b] = 0.f; }
        if (cbase < HID) {
            #pragma unroll
            for (int b = 0; b < NB; b++)
                #pragma unroll
                for (int i = 0; i < 8; i++) {
                    aq[b] = fmaf(xr[b][i], sqk[cbase + i], aq[b]);
                    ak[b] = fmaf(xr[b][i], sqk[104 + cbase + i], ak[b]);
                }
        }
        // butterfly over the 16-lane channel group (all 4 groups redundant)
        #pragma unroll
        for (int off = 1; off < 16; off <<= 1) {
            #pragma unroll
            for (int b = 0; b < NB; b++) {
                aq[b] += __shfl_xor(aq[b], off);
                ak[b] += __shfl_xor(ak[b], off);
            }
        }
        if (lane < 8) {
            float v = aq[0];
            #pragma unroll
            for (int b = 1; b < NB; b++) if (lane == b) v = aq[b];
            xbq[(size_t)s * NB + lane] = v;
        } else if (lane < 16) {
            int b0 = lane - 8;
            float v = ak[0];
            #pragma unroll
            for (int b = 1; b < NB; b++) if (b0 == b) v = ak[b];
            xbk[(size_t)s * NB + b0] = v;
        }
    }

    int beg = rowptr_s[s], end = rowptr_s[s + 1];
    if (beg == end) return;

    for (int w0 = beg; w0 < end; w0 += 64) {
        // one coalesced key load covers the next 64 edges (16 quads)
        int kw2 = (w0 + lane < end) ? skey_s[w0 + lane] : 0;
        int wend = w0 + 64 < end ? w0 + 64 : end;
        for (int p0 = w0; p0 < wend; p0 += 4) {
            int j = p0 - w0 + eg;              // < 64 always
            int rt = __shfl(kw2, j) & 63;      // zero memory ops in chain
            int p = p0 + eg;
            const float* cr = &scomp[rt * NB];
            float z[8] = {};
            #pragma unroll
            for (int b = 0; b < NB; b++) {
                float cb = cr[b];
                #pragma unroll
                for (int i = 0; i < 8; i++) z[i] = fmaf(cb, xr[b][i], z[i]);
            }
            ushort8 zz;
            #pragma unroll
            for (int i = 0; i < 8; i++) zz[i] = f2bf_rne(z[i]);
            // guard: cbase 104/112/120 would overrun the 104-ushort row
            if (p < end && cbase < ZW)
                *(ushort8*)&Z[(size_t)p * ZW + cbase] = zz;   // 16B, coalesced
        }
    }
}

// ==== dst-major: online softmax + paired-edge Z gather + bias; comp in LDS ====
// WB=1: write relu'd bf16 into padded layer-2 A buffer (hb) instead of f32 h.
template<int WB>
__global__ __launch_bounds__(256) void msg_soft(
        const int* __restrict__ rowptr, const int* __restrict__ skey,
        const int* __restrict__ zidx,
        const float* __restrict__ comp, const ushort_t* __restrict__ Z,
        const float* __restrict__ xbq, const float* __restrict__ xbk,
        const float* __restrict__ bias, float* __restrict__ h,
        ushort_t* __restrict__ hb) {
    __shared__ float scomp[R_REL * NB];   // 1.6 KB
    int tid = threadIdx.x;
    for (int i = tid; i < R_REL * NB; i += 256) scomp[i] = comp[i];
    __syncthreads();
    int wave = tid >> 6, lane = tid & 63;
    int d = blockIdx.x * 4 + wave;
    if (d >= N_NODES) return;
    int beg = rowptr[d], end = rowptr[d + 1];

    float4 qd0 = *(const float4*)&xbq[d * NB];
    float4 qd1 = *(const float4*)&xbq[d * NB + 4];

    int l5 = lane & 31;
    bool act = l5 < 25;
    int oc = l5 * 4;                  // channel base (4 channels per lane)
    f32x4 acc = {0.f, 0.f, 0.f, 0.f};
    float m = -1e30f, l = 0.f;

    for (int c0 = beg; c0 < end; c0 += 64) {
        int p = c0 + lane;
        bool valid = p < end;
        float a = -1e30f;
        int zi = 0;
        if (valid) {
            int key = skey[p];
            zi = zidx[p];
            int s = key >> 6, rt = key & 63;
            const float4 c0v = *(const float4*)&scomp[rt * NB];
            const float4 c1v = *(const float4*)&scomp[rt * NB + 4];
            const float4 k0v = *(const float4*)&xbk[s * NB];
            const float4 k1v = *(const float4*)&xbk[s * NB + 4];
            float qi = c0v.x*qd0.x + c0v.y*qd0.y + c0v.z*qd0.z + c0v.w*qd0.w
                     + c1v.x*qd1.x + c1v.y*qd1.y + c1v.z*qd1.z + c1v.w*qd1.w;
            float kj = c0v.x*k0v.x + c0v.y*k0v.y + c0v.z*k0v.z + c0v.w*k0v.w
                     + c1v.x*k1v.x + c1v.y*k1v.y + c1v.z*k1v.z + c1v.w*k1v.w;
            float av = qi + kj;
            a = av > 0.f ? av : 0.2f * av;  // leaky_relu 0.2
        }
        float cm = a;
        #pragma unroll
        for (int off = 32; off; off >>= 1) cm = fmaxf(cm, __shfl_xor(cm, off));
        float M = fmaxf(m, cm);
        float scale = __expf(m - M);
        acc *= scale; l *= scale; m = M;
        float wgt = valid ? __expf(a - M) : 0.f;
        float cs = wgt;
        #pragma unroll
        for (int off = 32; off; off >>= 1) cs += __shfl_xor(cs, off);
        l += cs;
        int cnt = end - c0; if (cnt > 64) cnt = 64;
        for (int j = 0; j < cnt; j += 2) {
            int jj = j + (lane >> 5);         // even half: j, odd half: j+1
            float wj = __shfl(wgt, jj);       // invalid -> 0
            int   zj = __shfl(zi, jj);
            if (act) {
                ushort4 zz = *(const ushort4*)&Z[(size_t)zj * ZW + oc];
                acc.x = fmaf(wj, bf2f(zz.x), acc.x);
                acc.y = fmaf(wj, bf2f(zz.y), acc.y);
                acc.z = fmaf(wj, bf2f(zz.z), acc.z);
                acc.w = fmaf(wj, bf2f(zz.w), acc.w);
            }
        }
    }
    // combine even/odd-edge halves: lane ℓ (<25) += lane ℓ+32
    #pragma unroll
    for (int i = 0; i < 4; i++) acc[i] += __shfl_xor(acc[i], 32);
    if (lane < 25) {
        float inv = 1.f / (l + 1e-16f);
        float4 r;
        r.x = bias[oc]     + acc.x * inv;
        r.y = bias[oc + 1] + acc.y * inv;
        r.z = bias[oc + 2] + acc.z * inv;
        r.w = bias[oc + 3] + acc.w * inv;
        if (WB) {
            ushort4 o;
            o.x = f2bf_rne(fmaxf(r.x, 0.f));
            o.y = f2bf_rne(fmaxf(r.y, 0.f));
            o.z = f2bf_rne(fmaxf(r.z, 0.f));
            o.w = f2bf_rne(fmaxf(r.w, 0.f));
            *(ushort4*)&hb[(size_t)d * KP2 + oc] = o;   // 8B aligned
        } else {
            *(float4*)&h[(size_t)d * HID + oc] = r;     // 16B aligned
        }
    }
}

// ---- pooled = mean(relu(h2[qidx])); out = pooled @ Wl^T + bl ----
__global__ __launch_bounds__(128) void head_kernel(
        const float* __restrict__ h2, const int* __restrict__ qidx,
        const float* __restrict__ Wl, const float* __restrict__ bl,
        float* __restrict__ out) {
    __shared__ float pooled[HID];
    int tid = threadIdx.x;
    if (tid < HID) {
        float s = 0.f;
        for (int i = 0; i < NQ; i++)
            s += fmaxf(h2[(size_t)qidx[i] * HID + tid], 0.f);
        pooled[tid] = s * (1.0f / NQ);
    }
    __syncthreads();
    if (tid < CLS) {
        float s = bl[tid];
        for (int o = 0; o < HID; o++) s = fmaf(pooled[o], Wl[tid * HID + o], s);
        out[tid] = s;
    }
}

extern "C" void kernel_launch(void* const* d_in, const int* in_sizes, int n_in,
                              void* d_out, int out_size, void* d_ws, size_t ws_size,
                              hipStream_t stream) {
    const float* x      = (const float*)d_in[0];
    const int*   ei     = (const int*)  d_in[1];
    const int*   et     = (const int*)  d_in[2];
    const int*   qidx   = (const int*)  d_in[3];
    const float* comp1  = (const float*)d_in[4];
    const float* basis1 = (const float*)d_in[5];
    const float* q1     = (const float*)d_in[6];
    const float* k1     = (const float*)d_in[7];
    const float* b1     = (const float*)d_in[8];
    const float* comp2  = (const float*)d_in[9];
    const float* basis2 = (const float*)d_in[10];
    const float* q2     = (const float*)d_in[11];
    const float* k2     = (const float*)d_in[12];
    const float* b2     = (const float*)d_in[13];
    const float* Wl     = (const float*)d_in[14];
    const float* bl     = (const float*)d_in[15];
    float* out = (float*)d_out;

    char* w = (char*)d_ws;
    size_t off = 0;
    auto alloc = [&](size_t nbytes) {
        void* p = (void*)(w + off);
        off += ((nbytes + 255) / 256) * 256;
        return p;
    };
    ushort_t* xbh    = (ushort_t*)alloc((size_t)N_NODES * OUTW * 2); // 32 MB
    ushort_t* Z      = (ushort_t*)alloc((size_t)E_EDGES * ZW * 2);   // 66.6 MB
    float*    h2     = (float*)alloc((size_t)N_NODES * HID * 4);     // 8 MB
    ushort_t* Bt1    = (ushort_t*)alloc((size_t)OUTW * KP1 * 2);     // 512 KB
    ushort_t* Bt2    = (ushort_t*)alloc((size_t)OUTW * KP2 * 2);     // 205 KB
    ushort_t* xbA    = (ushort_t*)alloc((size_t)MPAD * KP1 * 2);     // 12.9 MB
    ushort_t* hbA    = (ushort_t*)alloc((size_t)MPAD * KP2 * 2);     // 5.2 MB
    float*    xbq    = (float*)alloc((size_t)N_NODES * NB * 4);      // 640 KB
    float*    xbk    = (float*)alloc((size_t)N_NODES * NB * 4);      // 640 KB
    int*      deg_d  = (int*)alloc(N_NODES * 4);
    int*      deg_s  = (int*)alloc(N_NODES * 4);
    int*      rp_d   = (int*)alloc((N_NODES + 1) * 4);
    int*      rp_s   = (int*)alloc((N_NODES + 1) * 4);
    int*      cur_d  = (int*)alloc(N_NODES * 4);
    int*      cur_s  = (int*)alloc(N_NODES * 4);
    int*      bsum_d = (int*)alloc(SCAN_BLKS * 4);
    int*      bsum_s = (int*)alloc(SCAN_BLKS * 4);
    int*      skey   = (int*)alloc(E_EDGES * 4);
    int*      skey_s = (int*)alloc(E_EDGES * 4);
    int*      zidx   = (int*)alloc(E_EDGES * 4);

    // ---- fused preprocessing + CSR build ----
    prep_kernel<<<(PREP_TOT + 255) / 256, 256, 0, stream>>>(
        basis1, Bt1, basis2, Bt2, x, xbA, hbA, deg_d, deg_s);
    hist2_kernel<<<(E_EDGES + 255) / 256, 256, 0, stream>>>(ei, deg_d, deg_s);
    scan1_both<<<2 * SCAN_BLKS, 256, 0, stream>>>(deg_d, rp_d, bsum_d, deg_s, rp_s, bsum_s);
    scan2_both<<<2, 128, 0, stream>>>(bsum_d, rp_d, bsum_s, rp_s);
    scan3_both<<<2 * SCAN_BLKS, 256, 0, stream>>>(rp_d, bsum_d, cur_d, rp_s, bsum_s, cur_s);
    scatter_both<<<(E_EDGES + 255) / 256, 256, 0, stream>>>(ei, et, cur_d, cur_s, skey, skey_s, zidx);

    // ---- layer 1 (msg_soft writes relu'd bf16 straight into hbA) ----
    gemm_mfma<KP1><<<10 * GEMM_RG, 512, 0, stream>>>(xbA, Bt1, xbh, N_NODES);
    compute_z<<<(N_NODES + 3) / 4, 256, 0, stream>>>(rp_s, skey_s, comp1, xbh, Z, q1, k1, xbq, xbk);
    msg_soft<1><<<(N_NODES + 3) / 4, 256, 0, stream>>>(rp_d, skey, zidx, comp1, Z, xbq, xbk, b1, (float*)nullptr, hbA);

    // ---- layer 2 ----
    gemm_mfma<KP2><<<10 * GEMM_RG, 512, 0, stream>>>(hbA, Bt2, xbh, N_NODES);
    compute_z<<<(N_NODES + 3) / 4, 256, 0, stream>>>(rp_s, skey_s, comp2, xbh, Z, q2, k2, xbq, xbk);
    msg_soft<0><<<(N_NODES + 3) / 4, 256, 0, stream>>>(rp_d, skey, zidx, comp2, Z, xbq, xbk, b2, h2, (ushort_t*)nullptr);

    head_kernel<<<1, 128, 0, stream>>>(h2, qidx, Wl, bl, out);
}